// Round 2
// baseline (612.603 us; speedup 1.0000x reference)
//
#include <hip/hip_runtime.h>

// OneHeadAttention: B=4, S=4096, D=256.
// out = [z (4*4096*256 fp32) | attn (4*4096*4096 fp32)]
//
// Pipeline:
//  k_wt      : W* fp32 [k][n] -> bf16 Wt [n][k]
//  k_pgemm3  : q,k,v fp32 -> (convert in-kernel) @ Wt + b -> qp,kp bf16; v-path
//              epilogue transposes -> vpt [b][n][s] bf16  (one launch, grid.z=3)
//  k_qk      : E = exp(qp kp^T/16) causal; lower tiles -> eb bf16 (packed
//              triangular tile layout); masked tiles -> attn zeros (nt);
//              ps row-sum partials.  XCD-chunked swizzle.
//  k_pv2     : split-K, NO LDS pipeline: per block compute inv from ps,
//              stream eb -> attn fp32 = E*inv (nt), MFMA raw E @ V with
//              global->register fragments (no barriers in K-loop),
//              epilogue scales acc by inv, plain stores to per-kg ctxf slice
//  k_cvt     : sum active ctxf slices -> bf16 ctx
//  k_gemm    : z = ctx @ Wo + bo

typedef unsigned short u16;
typedef __attribute__((ext_vector_type(8))) short short8;
typedef __attribute__((ext_vector_type(4))) float f32x4;

struct __align__(8) us4 { u16 x, y, z, w; };

#define SEQ 4096
#define DIM 256

__device__ __forceinline__ u16 f2bf(float f) {
  unsigned int u = __float_as_uint(f);
  u += 0x7fffu + ((u >> 16) & 1u);
  return (u16)(u >> 16);
}
__device__ __forceinline__ float bf2f(u16 u) {
  return __uint_as_float(((unsigned int)u) << 16);
}

__device__ __forceinline__ void cp16(const void* g, void* l) {
  __builtin_amdgcn_global_load_lds((const __attribute__((address_space(1))) void*)g,
                                   (__attribute__((address_space(3))) void*)l, 16, 0, 0);
}

// ---------------- weight transpose ----------------
__global__ void k_wt(const float* __restrict__ Wq, const float* __restrict__ Wk,
                     const float* __restrict__ Wv, const float* __restrict__ Wo,
                     u16* __restrict__ wt) {
  __shared__ float t[32][33];
  const float* W = blockIdx.z == 0 ? Wq : blockIdx.z == 1 ? Wk : blockIdx.z == 2 ? Wv : Wo;
  u16* out = wt + (size_t)blockIdx.z * 65536;
  int n0 = blockIdx.x * 32, k0 = blockIdx.y * 32;
  int tx = threadIdx.x, ty = threadIdx.y;
  for (int i = 0; i < 4; i++)
    t[ty + i * 8][tx] = W[(size_t)(k0 + ty + i * 8) * 256 + n0 + tx];
  __syncthreads();
  for (int i = 0; i < 4; i++)
    out[(size_t)(n0 + ty + i * 8) * 256 + k0 + tx] = f2bf(t[tx][ty + i * 8]);
}

// ---------------- projection GEMMs, merged: z=0 -> qp, z=1 -> kp, z=2 -> vpt --
__global__ void k_pgemm3(const float* __restrict__ qin, const float* __restrict__ kin,
                         const float* __restrict__ vin, const u16* __restrict__ wtall,
                         const float* __restrict__ bq, const float* __restrict__ bk,
                         const float* __restrict__ bv,
                         u16* __restrict__ qp, u16* __restrict__ kp,
                         u16* __restrict__ vpt) {
  __shared__ __align__(16) char smem[34816];  // staging 16KB | TRANS epi 34816B
  const int z = blockIdx.z;
  const float* A = z == 0 ? qin : z == 1 ? kin : vin;
  const u16* Wt = wtall + (size_t)z * 65536;
  const float* bias = z == 0 ? bq : z == 1 ? bk : bv;
  u16* outp = z == 0 ? qp : z == 1 ? kp : vpt;
  const bool TRANS = (z == 2);

  u16* Asm = (u16*)smem;
  u16* Bsm = Asm + 4096;
  u16* tb = (u16*)smem;
  const int tid = threadIdx.x;
  const int lane = tid & 63, w = tid >> 6;
  const int wr = w >> 1, wc = w & 1;
  const int quad = lane >> 4, m16 = lane & 15;
  const int m0 = blockIdx.y * 128, n0 = blockIdx.x * 128;

  f32x4 zero = {0.f, 0.f, 0.f, 0.f};
  f32x4 acc[4][4];
  for (int i = 0; i < 4; i++)
    for (int j = 0; j < 4; j++) acc[i][j] = zero;

  for (int kk = 0; kk < 8; ++kk) {
    const int k0 = kk * 32;
    for (int h = 0; h < 2; ++h) {
      int c = tid + h * 256;
      int row = c >> 2, sub = c & 3;
      cp16(Wt + (size_t)(n0 + row) * 256 + k0 + sub * 8, Bsm + c * 8);
    }
    for (int h = 0; h < 4; ++h) {
      int idx = h * 256 + tid;
      int row = idx >> 3, q4 = idx & 7;
      float4 a4 = *(const float4*)(A + (size_t)(m0 + row) * 256 + k0 + q4 * 4);
      us4 o;
      o.x = f2bf(a4.x); o.y = f2bf(a4.y); o.z = f2bf(a4.z); o.w = f2bf(a4.w);
      *(us4*)(Asm + row * 32 + q4 * 4) = o;
    }
    __syncthreads();
    short8 a[4], b[4];
    for (int i = 0; i < 4; ++i)
      a[i] = *(const short8*)(Asm + (wr * 64 + i * 16 + m16) * 32 + quad * 8);
    for (int j = 0; j < 4; ++j)
      b[j] = *(const short8*)(Bsm + (wc * 64 + j * 16 + m16) * 32 + quad * 8);
    for (int i = 0; i < 4; ++i)
      for (int j = 0; j < 4; ++j)
        acc[i][j] = __builtin_amdgcn_mfma_f32_16x16x32_bf16(a[i], b[j], acc[i][j], 0, 0, 0);
    __syncthreads();
  }

  if (!TRANS) {
    for (int j = 0; j < 4; ++j) {
      int gn = n0 + wc * 64 + j * 16 + m16;
      float bvx = bias[gn];
      for (int i = 0; i < 4; ++i) {
        int gm = m0 + wr * 64 + i * 16 + quad * 4;
        for (int r = 0; r < 4; ++r)
          outp[(size_t)(gm + r) * 256 + gn] = f2bf(acc[i][j][r] + bvx);
      }
    }
  } else {
    // transpose epilogue -> vpt[b][n][s]
    for (int j = 0; j < 4; ++j) {
      int cn = wc * 64 + j * 16 + m16;
      float bvx = bias[n0 + cn];
      for (int i = 0; i < 4; ++i) {
        int rm = wr * 64 + i * 16 + quad * 4;
        us4 o;
        o.x = f2bf(acc[i][j][0] + bvx); o.y = f2bf(acc[i][j][1] + bvx);
        o.z = f2bf(acc[i][j][2] + bvx); o.w = f2bf(acc[i][j][3] + bvx);
        *(us4*)(tb + cn * 136 + rm) = o;
      }
    }
    __syncthreads();
    int b = m0 >> 12, s0 = m0 & 4095;
    u16* dst = outp + ((size_t)b << 20);
    for (int it = 0; it < 8; ++it) {
      int idx = it * 256 + tid;
      int n = idx >> 4, m8 = idx & 15;
      short8 v8 = *(const short8*)(tb + n * 136 + m8 * 8);
      *(short8*)(dst + (size_t)(n0 + n) * 4096 + s0 + m8 * 8) = v8;
    }
  }
}

// ---------------- QK^T, exp, causal ----------------------------------------
// eb is PACKED triangular: tile (qt,kt), kt<=qt, at index qt*(qt+1)/2+kt,
// each tile 128x128 bf16 contiguous (32KB).  XCD-chunked swizzle on work id.
__global__ void k_qk(const u16* __restrict__ qp, const u16* __restrict__ kp,
                     u16* __restrict__ eb, float* __restrict__ attn,
                     float* __restrict__ ps) {
  // bijective XCD swizzle: 4096 blocks, 8 XCDs -> each XCD a contiguous chunk
  int lin = blockIdx.x + (blockIdx.y << 5) + (blockIdx.z << 10);
  int wid = (lin & 7) * 512 + (lin >> 3);
  const int kt = wid & 31, qt = (wid >> 5) & 31, bz = wid >> 10;
  const int tid = threadIdx.x;
  const int q0 = qt * 128, k0t = kt * 128;

  if (kt > qt) {  // fully masked: attn zeros only
    float* attnb = attn + ((size_t)bz << 24);
    f32x4 z4 = {0.f, 0.f, 0.f, 0.f};
    for (int s = 0; s < 16; ++s) {
      int idx = tid + s * 256;
      int row = idx >> 5, c4 = idx & 31;
      __builtin_nontemporal_store(z4,
          (f32x4*)(attnb + (size_t)(q0 + row) * 4096 + k0t + c4 * 4));
    }
    return;
  }

  __shared__ __align__(16) char smem[34816];  // staging 16KB | epi u16 128x136
  u16* Asm = (u16*)smem;
  u16* Bsm = Asm + 4096;
  u16* epi = (u16*)smem;
  __shared__ float prow[2][128];

  const int lane = tid & 63, w = tid >> 6;
  const int wr = w >> 1, wc = w & 1;
  const int quad = lane >> 4, m16 = lane & 15;
  const u16* Ab = qp + ((size_t)bz << 20);
  const u16* Bb = kp + ((size_t)bz << 20);

  f32x4 zero = {0.f, 0.f, 0.f, 0.f};
  f32x4 acc[4][4];
  for (int i = 0; i < 4; i++)
    for (int j = 0; j < 4; j++) acc[i][j] = zero;

  for (int kk = 0; kk < 8; ++kk) {
    const int k0 = kk * 32;
    for (int h = 0; h < 2; ++h) {
      int c = tid + h * 256;
      int row = c >> 2, sub = c & 3;
      cp16(Ab + (size_t)(q0 + row) * 256 + k0 + sub * 8, Asm + c * 8);
      cp16(Bb + (size_t)(k0t + row) * 256 + k0 + sub * 8, Bsm + c * 8);
    }
    __syncthreads();
    short8 a[4], b[4];
    for (int i = 0; i < 4; ++i)
      a[i] = *(const short8*)(Asm + (wr * 64 + i * 16 + m16) * 32 + quad * 8);
    for (int j = 0; j < 4; ++j)
      b[j] = *(const short8*)(Bsm + (wc * 64 + j * 16 + m16) * 32 + quad * 8);
    for (int i = 0; i < 4; ++i)
      for (int j = 0; j < 4; ++j)
        acc[i][j] = __builtin_amdgcn_mfma_f32_16x16x32_bf16(a[i], b[j], acc[i][j], 0, 0, 0);
    __syncthreads();
  }

  // exp + causal mask + row-sum partials
  float rs[4][4];
  for (int i = 0; i < 4; i++)
    for (int r = 0; r < 4; r++) rs[i][r] = 0.f;
  for (int i = 0; i < 4; ++i) {
    int gq = q0 + wr * 64 + i * 16 + quad * 4;
    for (int j = 0; j < 4; ++j) {
      int gk = k0t + wc * 64 + j * 16 + m16;
      for (int r = 0; r < 4; ++r) {
        float e = (gk <= gq + r) ? __expf(acc[i][j][r] * 0.0625f) : 0.f;
        acc[i][j][r] = e;
        rs[i][r] += e;
      }
    }
  }
  for (int off = 1; off < 16; off <<= 1)
    for (int i = 0; i < 4; ++i)
      for (int r = 0; r < 4; ++r) rs[i][r] += __shfl_xor(rs[i][r], off, 64);
  if (m16 == 0)
    for (int i = 0; i < 4; ++i)
      for (int r = 0; r < 4; ++r)
        prow[wc][wr * 64 + i * 16 + quad * 4 + r] = rs[i][r];

  // dump E bf16 into LDS, then coalesced 16B nt stores to packed eb tile
  for (int i = 0; i < 4; ++i)
    for (int j = 0; j < 4; ++j) {
      int rl = wr * 64 + i * 16 + quad * 4;
      int cl = wc * 64 + j * 16 + m16;
      for (int r = 0; r < 4; ++r) epi[(rl + r) * 136 + cl] = f2bf(acc[i][j][r]);
    }
  __syncthreads();

  u16* ebt = eb + ((size_t)bz * 528 + (size_t)(qt * (qt + 1) / 2 + kt)) * 16384;
  for (int it = 0; it < 8; ++it) {
    int idx = it * 256 + tid;
    int row = idx >> 4, m8 = idx & 15;
    short8 v8 = *(const short8*)(epi + row * 136 + m8 * 8);
    __builtin_nontemporal_store(v8, (short8*)(ebt + row * 128 + m8 * 8));
  }
  if (tid < 128)
    ps[(size_t)(bz * 32 + kt) * 4096 + q0 + tid] = prow[0][tid] + prow[1][tid];
}

// ---------------- split-K PV: no LDS pipeline, no K-loop barriers -----------
// inv computed in-block from ps; A frags straight from packed eb (L2-hot),
// B frags straight from vpt; acc scaled by inv in epilogue.
__global__ void __launch_bounds__(512, 4) k_pv2(const u16* __restrict__ eb,
                                                const u16* __restrict__ vpt,
                                                const float* __restrict__ ps,
                                                float* __restrict__ attn,
                                                float* __restrict__ ctxf) {
  // bijective XCD swizzle over 512 blocks
  int lin = blockIdx.x + (blockIdx.y << 2) + (blockIdx.z << 7);  // kg+4*qt+128*bz
  int wid = (lin & 7) * 64 + (lin >> 3);
  const int qt = wid & 31, kg = (wid >> 5) & 3, bz = wid >> 7;
  const int k_lo = kg * 1024;
  const int k_hi = min((qt + 1) * 128, k_lo + 1024);
  if (k_lo >= k_hi) return;

  __shared__ float inv_lds[128];

  const int tid = threadIdx.x;
  const int lane = tid & 63, w = tid >> 6;
  const int wr = w >> 2, wc = w & 3;       // wr: q-half(64), wc: n-quarter(64)
  const int quad = lane >> 4, m16 = lane & 15;
  const int q0 = qt * 128;
  const u16* ebq = eb + ((size_t)bz * 528 + (size_t)(qt * (qt + 1) / 2)) * 16384;
  float* attnb = attn + ((size_t)bz << 24);
  const u16* vb = vpt + ((size_t)bz << 20);

  if (tid < 128) {
    float s = 0.f;
    for (int kt = 0; kt <= qt; ++kt)
      s += ps[(size_t)(bz * 32 + kt) * 4096 + q0 + tid];
    inv_lds[tid] = 1.f / s;
  }
  __syncthreads();

  f32x4 zero = {0.f, 0.f, 0.f, 0.f};
  f32x4 acc[4][4];
  for (int i = 0; i < 4; i++)
    for (int j = 0; j < 4; j++) acc[i][j] = zero;

  for (int kt0 = k_lo; kt0 < k_hi; kt0 += 128) {
    const u16* ebtile = ebq + (size_t)(kt0 >> 7) * 16384;
    // attn = E * inv (fp32, nt store). Regular E loads populate L2 for frags.
    for (int p = 0; p < 4; ++p) {
      int idx = p * 512 + tid;
      int row = idx >> 4, c8 = idx & 15;
      short8 e8 = *(const short8*)(ebtile + row * 128 + c8 * 8);
      float ivr = inv_lds[row];
      f32x4 lo, hi;
      for (int t = 0; t < 4; ++t) lo[t] = bf2f((u16)e8[t]) * ivr;
      for (int t = 0; t < 4; ++t) hi[t] = bf2f((u16)e8[t + 4]) * ivr;
      float* dst = attnb + (size_t)(q0 + row) * 4096 + kt0 + c8 * 8;
      __builtin_nontemporal_store(lo, (f32x4*)dst);
      __builtin_nontemporal_store(hi, (f32x4*)(dst + 4));
    }
    // MFMA with global->register fragments, no barriers
    for (int ks = 0; ks < 4; ++ks) {
      short8 a[4], b[4];
      for (int i = 0; i < 4; ++i)
        a[i] = *(const short8*)(ebtile + (wr * 64 + i * 16 + m16) * 128 + ks * 32 + quad * 8);
      for (int j = 0; j < 4; ++j)
        b[j] = *(const short8*)(vb + (size_t)(wc * 64 + j * 16 + m16) * 4096 + kt0 + ks * 32 + quad * 8);
      for (int i = 0; i < 4; ++i)
        for (int j = 0; j < 4; ++j)
          acc[i][j] = __builtin_amdgcn_mfma_f32_16x16x32_bf16(a[i], b[j], acc[i][j], 0, 0, 0);
    }
  }

  // epilogue: scale by inv, plain coalesced stores to this kg's private slice
  float* ctxs = ctxf + ((size_t)(kg * 4 + bz) << 20);
  for (int i = 0; i < 4; ++i) {
    int rl = wr * 64 + i * 16 + quad * 4;
    for (int j = 0; j < 4; ++j) {
      int gn = wc * 64 + j * 16 + m16;
      for (int r = 0; r < 4; ++r)
        ctxs[(size_t)(q0 + rl + r) * 256 + gn] = acc[i][j][r] * inv_lds[rl + r];
    }
  }
}

// ---------------- sum active ctxf slices -> bf16 ctx ----------------
__global__ void k_cvt(const float* __restrict__ ctxf, u16* __restrict__ ctx) {
  size_t i4 = (size_t)blockIdx.x * 256 + threadIdx.x;  // float4 index over [4][4096][64]
  int bz = (int)(i4 >> 18);
  size_t rem4 = i4 & (((size_t)1 << 18) - 1);
  int qrow = (int)(rem4 >> 6);
  int nact = (qrow >> 10) + 1;  // active kg slices for this q-row
  const float4* base = (const float4*)ctxf;
  float4 s = base[((size_t)bz << 18) + rem4];
  for (int kg = 1; kg < nact; ++kg) {
    float4 t = base[((size_t)(kg * 4 + bz) << 18) + rem4];
    s.x += t.x; s.y += t.y; s.z += t.z; s.w += t.w;
  }
  us4 o;
  o.x = f2bf(s.x); o.y = f2bf(s.y); o.z = f2bf(s.z); o.w = f2bf(s.w);
  ((us4*)ctx)[i4] = o;
}

// ---------------- bf16-input GEMM (final projection) ----------------
template <bool OUT_BF16>
__global__ void k_gemm(const u16* __restrict__ A, const u16* __restrict__ Wt,
                       const float* __restrict__ bias, void* __restrict__ outp) {
  __shared__ u16 Asm[128 * 32];
  __shared__ u16 Bsm[128 * 32];
  const int tid = threadIdx.x;
  const int lane = tid & 63, w = tid >> 6;
  const int wr = w >> 1, wc = w & 1;
  const int quad = lane >> 4, m16 = lane & 15;
  const int m0 = blockIdx.y * 128, n0 = blockIdx.x * 128;

  f32x4 zero = {0.f, 0.f, 0.f, 0.f};
  f32x4 acc[4][4];
  for (int i = 0; i < 4; i++)
    for (int j = 0; j < 4; j++) acc[i][j] = zero;

  for (int kk = 0; kk < 8; ++kk) {
    const int k0 = kk * 32;
    for (int h = 0; h < 2; ++h) {
      int c = tid + h * 256;
      int row = c >> 2, sub = c & 3;
      cp16(A + (size_t)(m0 + row) * 256 + k0 + sub * 8, Asm + c * 8);
      cp16(Wt + (size_t)(n0 + row) * 256 + k0 + sub * 8, Bsm + c * 8);
    }
    __syncthreads();
    short8 a[4], b[4];
    for (int i = 0; i < 4; ++i)
      a[i] = *(const short8*)(Asm + (wr * 64 + i * 16 + m16) * 32 + quad * 8);
    for (int j = 0; j < 4; ++j)
      b[j] = *(const short8*)(Bsm + (wc * 64 + j * 16 + m16) * 32 + quad * 8);
    for (int i = 0; i < 4; ++i)
      for (int j = 0; j < 4; ++j)
        acc[i][j] = __builtin_amdgcn_mfma_f32_16x16x32_bf16(a[i], b[j], acc[i][j], 0, 0, 0);
    __syncthreads();
  }

  for (int j = 0; j < 4; ++j) {
    int gn = n0 + wc * 64 + j * 16 + m16;
    float bv = bias[gn];
    for (int i = 0; i < 4; ++i) {
      int gm = m0 + wr * 64 + i * 16 + quad * 4;
      for (int r = 0; r < 4; ++r) {
        float val = acc[i][j][r] + bv;
        if (OUT_BF16)
          ((u16*)outp)[(size_t)(gm + r) * 256 + gn] = f2bf(val);
        else
          ((float*)outp)[(size_t)(gm + r) * 256 + gn] = val;
      }
    }
  }
}

extern "C" void kernel_launch(void* const* d_in, const int* in_sizes, int n_in,
                              void* d_out, int out_size, void* d_ws, size_t ws_size,
                              hipStream_t stream) {
  const float* q  = (const float*)d_in[0];
  const float* k  = (const float*)d_in[1];
  const float* v  = (const float*)d_in[2];
  const float* Wq = (const float*)d_in[4];
  const float* bq = (const float*)d_in[5];
  const float* Wk = (const float*)d_in[6];
  const float* bk = (const float*)d_in[7];
  const float* Wv = (const float*)d_in[8];
  const float* bv = (const float*)d_in[9];
  const float* Wo = (const float*)d_in[10];
  const float* bo = (const float*)d_in[11];

  const size_t MD = (size_t)16384 * 256;
  u16* qp  = (u16*)d_ws;
  u16* kp  = qp + MD;
  u16* vpt = kp + MD;                         // [4][256][4096]
  u16* ctx = vpt + MD;
  u16* wt  = ctx + MD;                        // 4 x 256x256 bf16
  float* ps   = (float*)(wt + 4 * 65536);     // [4][32][4096]
  float* ctxf = ps + (size_t)4 * 32 * 4096;   // [4 kg][4 b][4096][256] fp32 = 64MB
  u16* eb = (u16*)(ctxf + (size_t)16 * 1024 * 1024);  // packed tri [4][528][16384] bf16

  float* zout = (float*)d_out;
  float* attn = zout + (size_t)4 * 4096 * 256;

  k_wt<<<dim3(8, 8, 4), dim3(32, 8), 0, stream>>>(Wq, Wk, Wv, Wo, wt);
  k_pgemm3<<<dim3(2, 128, 3), 256, 0, stream>>>(q, k, v, wt, bq, bk, bv, qp, kp, vpt);
  k_qk<<<dim3(32, 32, 4), 256, 0, stream>>>(qp, kp, eb, attn, ps);
  k_pv2<<<dim3(4, 32, 4), 512, 0, stream>>>(eb, vpt, ps, attn, ctxf);
  k_cvt<<<4096, 256, 0, stream>>>(ctxf, ctx);
  k_gemm<false><<<dim3(2, 128), 256, 0, stream>>>(ctx, wt + 3 * 65536, bo, zout);
}

// Round 3
// 595.659 us; speedup vs baseline: 1.0284x; 1.0284x over previous
//
#include <hip/hip_runtime.h>

// OneHeadAttention: B=4, S=4096, D=256.
// out = [z (4*4096*256 fp32) | attn (4*4096*4096 fp32)]
//
// Pipeline:
//  k_wt      : W* fp32 [k][n] -> bf16 Wt [n][k]
//  k_pgemm3  : q,k,v fp32 -> (convert in-kernel) @ Wt + b -> qp,kp bf16; v-path
//              epilogue transposes -> vpt [b][n][s] bf16  (one launch, grid.z=3)
//  k_qk      : E = exp(qp kp^T/16) causal; lower tiles -> eb bf16 (packed
//              triangular tile layout); masked tiles -> attn zeros (nt);
//              ps row-sum partials.  XCD-chunked swizzle.
//  k_pv2     : split-K, NO LDS pipeline: per block compute inv from ps,
//              stream eb -> attn fp32 = E*inv (nt), MFMA raw E @ V with
//              global->register fragments (no barriers in K-loop),
//              epilogue scales acc by inv, plain stores to per-kg ctxf slice.
//              NOTE: no min-waves clamp in launch_bounds — acc[4][4] alone is
//              64 VGPRs; clamping to 64 total spills acc to scratch (R2: 230us,
//              +90MB write traffic).
//  k_cvt     : sum active ctxf slices -> bf16 ctx
//  k_gemm    : z = ctx @ Wo + bo

typedef unsigned short u16;
typedef __attribute__((ext_vector_type(8))) short short8;
typedef __attribute__((ext_vector_type(4))) float f32x4;

struct __align__(8) us4 { u16 x, y, z, w; };

#define SEQ 4096
#define DIM 256

__device__ __forceinline__ u16 f2bf(float f) {
  unsigned int u = __float_as_uint(f);
  u += 0x7fffu + ((u >> 16) & 1u);
  return (u16)(u >> 16);
}
__device__ __forceinline__ float bf2f(u16 u) {
  return __uint_as_float(((unsigned int)u) << 16);
}

__device__ __forceinline__ void cp16(const void* g, void* l) {
  __builtin_amdgcn_global_load_lds((const __attribute__((address_space(1))) void*)g,
                                   (__attribute__((address_space(3))) void*)l, 16, 0, 0);
}

// ---------------- weight transpose ----------------
__global__ void k_wt(const float* __restrict__ Wq, const float* __restrict__ Wk,
                     const float* __restrict__ Wv, const float* __restrict__ Wo,
                     u16* __restrict__ wt) {
  __shared__ float t[32][33];
  const float* W = blockIdx.z == 0 ? Wq : blockIdx.z == 1 ? Wk : blockIdx.z == 2 ? Wv : Wo;
  u16* out = wt + (size_t)blockIdx.z * 65536;
  int n0 = blockIdx.x * 32, k0 = blockIdx.y * 32;
  int tx = threadIdx.x, ty = threadIdx.y;
  for (int i = 0; i < 4; i++)
    t[ty + i * 8][tx] = W[(size_t)(k0 + ty + i * 8) * 256 + n0 + tx];
  __syncthreads();
  for (int i = 0; i < 4; i++)
    out[(size_t)(n0 + ty + i * 8) * 256 + k0 + tx] = f2bf(t[tx][ty + i * 8]);
}

// ---------------- projection GEMMs, merged: z=0 -> qp, z=1 -> kp, z=2 -> vpt --
__global__ void k_pgemm3(const float* __restrict__ qin, const float* __restrict__ kin,
                         const float* __restrict__ vin, const u16* __restrict__ wtall,
                         const float* __restrict__ bq, const float* __restrict__ bk,
                         const float* __restrict__ bv,
                         u16* __restrict__ qp, u16* __restrict__ kp,
                         u16* __restrict__ vpt) {
  __shared__ __align__(16) char smem[34816];  // staging 16KB | TRANS epi 34816B
  const int z = blockIdx.z;
  const float* A = z == 0 ? qin : z == 1 ? kin : vin;
  const u16* Wt = wtall + (size_t)z * 65536;
  const float* bias = z == 0 ? bq : z == 1 ? bk : bv;
  u16* outp = z == 0 ? qp : z == 1 ? kp : vpt;
  const bool TRANS = (z == 2);

  u16* Asm = (u16*)smem;
  u16* Bsm = Asm + 4096;
  u16* tb = (u16*)smem;
  const int tid = threadIdx.x;
  const int lane = tid & 63, w = tid >> 6;
  const int wr = w >> 1, wc = w & 1;
  const int quad = lane >> 4, m16 = lane & 15;
  const int m0 = blockIdx.y * 128, n0 = blockIdx.x * 128;

  f32x4 zero = {0.f, 0.f, 0.f, 0.f};
  f32x4 acc[4][4];
  for (int i = 0; i < 4; i++)
    for (int j = 0; j < 4; j++) acc[i][j] = zero;

  for (int kk = 0; kk < 8; ++kk) {
    const int k0 = kk * 32;
    for (int h = 0; h < 2; ++h) {
      int c = tid + h * 256;
      int row = c >> 2, sub = c & 3;
      cp16(Wt + (size_t)(n0 + row) * 256 + k0 + sub * 8, Bsm + c * 8);
    }
    for (int h = 0; h < 4; ++h) {
      int idx = h * 256 + tid;
      int row = idx >> 3, q4 = idx & 7;
      float4 a4 = *(const float4*)(A + (size_t)(m0 + row) * 256 + k0 + q4 * 4);
      us4 o;
      o.x = f2bf(a4.x); o.y = f2bf(a4.y); o.z = f2bf(a4.z); o.w = f2bf(a4.w);
      *(us4*)(Asm + row * 32 + q4 * 4) = o;
    }
    __syncthreads();
    short8 a[4], b[4];
    for (int i = 0; i < 4; ++i)
      a[i] = *(const short8*)(Asm + (wr * 64 + i * 16 + m16) * 32 + quad * 8);
    for (int j = 0; j < 4; ++j)
      b[j] = *(const short8*)(Bsm + (wc * 64 + j * 16 + m16) * 32 + quad * 8);
    for (int i = 0; i < 4; ++i)
      for (int j = 0; j < 4; ++j)
        acc[i][j] = __builtin_amdgcn_mfma_f32_16x16x32_bf16(a[i], b[j], acc[i][j], 0, 0, 0);
    __syncthreads();
  }

  if (!TRANS) {
    for (int j = 0; j < 4; ++j) {
      int gn = n0 + wc * 64 + j * 16 + m16;
      float bvx = bias[gn];
      for (int i = 0; i < 4; ++i) {
        int gm = m0 + wr * 64 + i * 16 + quad * 4;
        for (int r = 0; r < 4; ++r)
          outp[(size_t)(gm + r) * 256 + gn] = f2bf(acc[i][j][r] + bvx);
      }
    }
  } else {
    // transpose epilogue -> vpt[b][n][s]
    for (int j = 0; j < 4; ++j) {
      int cn = wc * 64 + j * 16 + m16;
      float bvx = bias[n0 + cn];
      for (int i = 0; i < 4; ++i) {
        int rm = wr * 64 + i * 16 + quad * 4;
        us4 o;
        o.x = f2bf(acc[i][j][0] + bvx); o.y = f2bf(acc[i][j][1] + bvx);
        o.z = f2bf(acc[i][j][2] + bvx); o.w = f2bf(acc[i][j][3] + bvx);
        *(us4*)(tb + cn * 136 + rm) = o;
      }
    }
    __syncthreads();
    int b = m0 >> 12, s0 = m0 & 4095;
    u16* dst = outp + ((size_t)b << 20);
    for (int it = 0; it < 8; ++it) {
      int idx = it * 256 + tid;
      int n = idx >> 4, m8 = idx & 15;
      short8 v8 = *(const short8*)(tb + n * 136 + m8 * 8);
      *(short8*)(dst + (size_t)(n0 + n) * 4096 + s0 + m8 * 8) = v8;
    }
  }
}

// ---------------- QK^T, exp, causal ----------------------------------------
// eb is PACKED triangular: tile (qt,kt), kt<=qt, at index qt*(qt+1)/2+kt,
// each tile 128x128 bf16 contiguous (32KB).  XCD-chunked swizzle on work id.
__global__ void k_qk(const u16* __restrict__ qp, const u16* __restrict__ kp,
                     u16* __restrict__ eb, float* __restrict__ attn,
                     float* __restrict__ ps) {
  // bijective XCD swizzle: 4096 blocks, 8 XCDs -> each XCD a contiguous chunk
  int lin = blockIdx.x + (blockIdx.y << 5) + (blockIdx.z << 10);
  int wid = (lin & 7) * 512 + (lin >> 3);
  const int kt = wid & 31, qt = (wid >> 5) & 31, bz = wid >> 10;
  const int tid = threadIdx.x;
  const int q0 = qt * 128, k0t = kt * 128;

  if (kt > qt) {  // fully masked: attn zeros only
    float* attnb = attn + ((size_t)bz << 24);
    f32x4 z4 = {0.f, 0.f, 0.f, 0.f};
    for (int s = 0; s < 16; ++s) {
      int idx = tid + s * 256;
      int row = idx >> 5, c4 = idx & 31;
      __builtin_nontemporal_store(z4,
          (f32x4*)(attnb + (size_t)(q0 + row) * 4096 + k0t + c4 * 4));
    }
    return;
  }

  __shared__ __align__(16) char smem[34816];  // staging 16KB | epi u16 128x136
  u16* Asm = (u16*)smem;
  u16* Bsm = Asm + 4096;
  u16* epi = (u16*)smem;
  __shared__ float prow[2][128];

  const int lane = tid & 63, w = tid >> 6;
  const int wr = w >> 1, wc = w & 1;
  const int quad = lane >> 4, m16 = lane & 15;
  const u16* Ab = qp + ((size_t)bz << 20);
  const u16* Bb = kp + ((size_t)bz << 20);

  f32x4 zero = {0.f, 0.f, 0.f, 0.f};
  f32x4 acc[4][4];
  for (int i = 0; i < 4; i++)
    for (int j = 0; j < 4; j++) acc[i][j] = zero;

  for (int kk = 0; kk < 8; ++kk) {
    const int k0 = kk * 32;
    for (int h = 0; h < 2; ++h) {
      int c = tid + h * 256;
      int row = c >> 2, sub = c & 3;
      cp16(Ab + (size_t)(q0 + row) * 256 + k0 + sub * 8, Asm + c * 8);
      cp16(Bb + (size_t)(k0t + row) * 256 + k0 + sub * 8, Bsm + c * 8);
    }
    __syncthreads();
    short8 a[4], b[4];
    for (int i = 0; i < 4; ++i)
      a[i] = *(const short8*)(Asm + (wr * 64 + i * 16 + m16) * 32 + quad * 8);
    for (int j = 0; j < 4; ++j)
      b[j] = *(const short8*)(Bsm + (wc * 64 + j * 16 + m16) * 32 + quad * 8);
    for (int i = 0; i < 4; ++i)
      for (int j = 0; j < 4; ++j)
        acc[i][j] = __builtin_amdgcn_mfma_f32_16x16x32_bf16(a[i], b[j], acc[i][j], 0, 0, 0);
    __syncthreads();
  }

  // exp + causal mask + row-sum partials
  float rs[4][4];
  for (int i = 0; i < 4; i++)
    for (int r = 0; r < 4; r++) rs[i][r] = 0.f;
  for (int i = 0; i < 4; ++i) {
    int gq = q0 + wr * 64 + i * 16 + quad * 4;
    for (int j = 0; j < 4; ++j) {
      int gk = k0t + wc * 64 + j * 16 + m16;
      for (int r = 0; r < 4; ++r) {
        float e = (gk <= gq + r) ? __expf(acc[i][j][r] * 0.0625f) : 0.f;
        acc[i][j][r] = e;
        rs[i][r] += e;
      }
    }
  }
  for (int off = 1; off < 16; off <<= 1)
    for (int i = 0; i < 4; ++i)
      for (int r = 0; r < 4; ++r) rs[i][r] += __shfl_xor(rs[i][r], off, 64);
  if (m16 == 0)
    for (int i = 0; i < 4; ++i)
      for (int r = 0; r < 4; ++r)
        prow[wc][wr * 64 + i * 16 + quad * 4 + r] = rs[i][r];

  // dump E bf16 into LDS, then coalesced 16B nt stores to packed eb tile
  for (int i = 0; i < 4; ++i)
    for (int j = 0; j < 4; ++j) {
      int rl = wr * 64 + i * 16 + quad * 4;
      int cl = wc * 64 + j * 16 + m16;
      for (int r = 0; r < 4; ++r) epi[(rl + r) * 136 + cl] = f2bf(acc[i][j][r]);
    }
  __syncthreads();

  u16* ebt = eb + ((size_t)bz * 528 + (size_t)(qt * (qt + 1) / 2 + kt)) * 16384;
  for (int it = 0; it < 8; ++it) {
    int idx = it * 256 + tid;
    int row = idx >> 4, m8 = idx & 15;
    short8 v8 = *(const short8*)(epi + row * 136 + m8 * 8);
    __builtin_nontemporal_store(v8, (short8*)(ebt + row * 128 + m8 * 8));
  }
  if (tid < 128)
    ps[(size_t)(bz * 32 + kt) * 4096 + q0 + tid] = prow[0][tid] + prow[1][tid];
}

// ---------------- split-K PV: no LDS pipeline, no K-loop barriers -----------
// inv computed in-block from ps; A frags straight from packed eb (L2-hot),
// B frags straight from vpt; acc scaled by inv in epilogue.
__global__ void __launch_bounds__(512) k_pv2(const u16* __restrict__ eb,
                                             const u16* __restrict__ vpt,
                                             const float* __restrict__ ps,
                                             float* __restrict__ attn,
                                             float* __restrict__ ctxf) {
  // bijective XCD swizzle over 512 blocks
  int lin = blockIdx.x + (blockIdx.y << 2) + (blockIdx.z << 7);  // kg+4*qt+128*bz
  int wid = (lin & 7) * 64 + (lin >> 3);
  const int qt = wid & 31, kg = (wid >> 5) & 3, bz = wid >> 7;
  const int k_lo = kg * 1024;
  const int k_hi = min((qt + 1) * 128, k_lo + 1024);
  if (k_lo >= k_hi) return;

  __shared__ float inv_lds[128];

  const int tid = threadIdx.x;
  const int lane = tid & 63, w = tid >> 6;
  const int wr = w >> 2, wc = w & 3;       // wr: q-half(64), wc: n-quarter(64)
  const int quad = lane >> 4, m16 = lane & 15;
  const int q0 = qt * 128;
  const u16* ebq = eb + ((size_t)bz * 528 + (size_t)(qt * (qt + 1) / 2)) * 16384;
  float* attnb = attn + ((size_t)bz << 24);
  const u16* vb = vpt + ((size_t)bz << 20);

  if (tid < 128) {
    float s = 0.f;
    for (int kt = 0; kt <= qt; ++kt)
      s += ps[(size_t)(bz * 32 + kt) * 4096 + q0 + tid];
    inv_lds[tid] = 1.f / s;
  }
  __syncthreads();

  f32x4 zero = {0.f, 0.f, 0.f, 0.f};
  f32x4 acc[4][4];
  for (int i = 0; i < 4; i++)
    for (int j = 0; j < 4; j++) acc[i][j] = zero;

  for (int kt0 = k_lo; kt0 < k_hi; kt0 += 128) {
    const u16* ebtile = ebq + (size_t)(kt0 >> 7) * 16384;
    // attn = E * inv (fp32, nt store). Regular E loads populate L2 for frags.
    for (int p = 0; p < 4; ++p) {
      int idx = p * 512 + tid;
      int row = idx >> 4, c8 = idx & 15;
      short8 e8 = *(const short8*)(ebtile + row * 128 + c8 * 8);
      float ivr = inv_lds[row];
      f32x4 lo, hi;
      for (int t = 0; t < 4; ++t) lo[t] = bf2f((u16)e8[t]) * ivr;
      for (int t = 0; t < 4; ++t) hi[t] = bf2f((u16)e8[t + 4]) * ivr;
      float* dst = attnb + (size_t)(q0 + row) * 4096 + kt0 + c8 * 8;
      __builtin_nontemporal_store(lo, (f32x4*)dst);
      __builtin_nontemporal_store(hi, (f32x4*)(dst + 4));
    }
    // MFMA with global->register fragments, no barriers
    for (int ks = 0; ks < 4; ++ks) {
      short8 a[4], b[4];
      for (int i = 0; i < 4; ++i)
        a[i] = *(const short8*)(ebtile + (wr * 64 + i * 16 + m16) * 128 + ks * 32 + quad * 8);
      for (int j = 0; j < 4; ++j)
        b[j] = *(const short8*)(vb + (size_t)(wc * 64 + j * 16 + m16) * 4096 + kt0 + ks * 32 + quad * 8);
      for (int i = 0; i < 4; ++i)
        for (int j = 0; j < 4; ++j)
          acc[i][j] = __builtin_amdgcn_mfma_f32_16x16x32_bf16(a[i], b[j], acc[i][j], 0, 0, 0);
    }
  }

  // epilogue: scale by inv, plain coalesced stores to this kg's private slice
  float* ctxs = ctxf + ((size_t)(kg * 4 + bz) << 20);
  for (int i = 0; i < 4; ++i) {
    int rl = wr * 64 + i * 16 + quad * 4;
    for (int j = 0; j < 4; ++j) {
      int gn = wc * 64 + j * 16 + m16;
      for (int r = 0; r < 4; ++r)
        ctxs[(size_t)(q0 + rl + r) * 256 + gn] = acc[i][j][r] * inv_lds[rl + r];
    }
  }
}

// ---------------- sum active ctxf slices -> bf16 ctx ----------------
__global__ void k_cvt(const float* __restrict__ ctxf, u16* __restrict__ ctx) {
  size_t i4 = (size_t)blockIdx.x * 256 + threadIdx.x;  // float4 index over [4][4096][64]
  int bz = (int)(i4 >> 18);
  size_t rem4 = i4 & (((size_t)1 << 18) - 1);
  int qrow = (int)(rem4 >> 6);
  int nact = (qrow >> 10) + 1;  // active kg slices for this q-row
  const float4* base = (const float4*)ctxf;
  float4 s = base[((size_t)bz << 18) + rem4];
  for (int kg = 1; kg < nact; ++kg) {
    float4 t = base[((size_t)(kg * 4 + bz) << 18) + rem4];
    s.x += t.x; s.y += t.y; s.z += t.z; s.w += t.w;
  }
  us4 o;
  o.x = f2bf(s.x); o.y = f2bf(s.y); o.z = f2bf(s.z); o.w = f2bf(s.w);
  ((us4*)ctx)[i4] = o;
}

// ---------------- bf16-input GEMM (final projection) ----------------
template <bool OUT_BF16>
__global__ void k_gemm(const u16* __restrict__ A, const u16* __restrict__ Wt,
                       const float* __restrict__ bias, void* __restrict__ outp) {
  __shared__ u16 Asm[128 * 32];
  __shared__ u16 Bsm[128 * 32];
  const int tid = threadIdx.x;
  const int lane = tid & 63, w = tid >> 6;
  const int wr = w >> 1, wc = w & 1;
  const int quad = lane >> 4, m16 = lane & 15;
  const int m0 = blockIdx.y * 128, n0 = blockIdx.x * 128;

  f32x4 zero = {0.f, 0.f, 0.f, 0.f};
  f32x4 acc[4][4];
  for (int i = 0; i < 4; i++)
    for (int j = 0; j < 4; j++) acc[i][j] = zero;

  for (int kk = 0; kk < 8; ++kk) {
    const int k0 = kk * 32;
    for (int h = 0; h < 2; ++h) {
      int c = tid + h * 256;
      int row = c >> 2, sub = c & 3;
      cp16(A + (size_t)(m0 + row) * 256 + k0 + sub * 8, Asm + c * 8);
      cp16(Wt + (size_t)(n0 + row) * 256 + k0 + sub * 8, Bsm + c * 8);
    }
    __syncthreads();
    short8 a[4], b[4];
    for (int i = 0; i < 4; ++i)
      a[i] = *(const short8*)(Asm + (wr * 64 + i * 16 + m16) * 32 + quad * 8);
    for (int j = 0; j < 4; ++j)
      b[j] = *(const short8*)(Bsm + (wc * 64 + j * 16 + m16) * 32 + quad * 8);
    for (int i = 0; i < 4; ++i)
      for (int j = 0; j < 4; ++j)
        acc[i][j] = __builtin_amdgcn_mfma_f32_16x16x32_bf16(a[i], b[j], acc[i][j], 0, 0, 0);
    __syncthreads();
  }

  for (int j = 0; j < 4; ++j) {
    int gn = n0 + wc * 64 + j * 16 + m16;
    float bv = bias[gn];
    for (int i = 0; i < 4; ++i) {
      int gm = m0 + wr * 64 + i * 16 + quad * 4;
      for (int r = 0; r < 4; ++r) {
        float val = acc[i][j][r] + bv;
        if (OUT_BF16)
          ((u16*)outp)[(size_t)(gm + r) * 256 + gn] = f2bf(val);
        else
          ((float*)outp)[(size_t)(gm + r) * 256 + gn] = val;
      }
    }
  }
}

extern "C" void kernel_launch(void* const* d_in, const int* in_sizes, int n_in,
                              void* d_out, int out_size, void* d_ws, size_t ws_size,
                              hipStream_t stream) {
  const float* q  = (const float*)d_in[0];
  const float* k  = (const float*)d_in[1];
  const float* v  = (const float*)d_in[2];
  const float* Wq = (const float*)d_in[4];
  const float* bq = (const float*)d_in[5];
  const float* Wk = (const float*)d_in[6];
  const float* bk = (const float*)d_in[7];
  const float* Wv = (const float*)d_in[8];
  const float* bv = (const float*)d_in[9];
  const float* Wo = (const float*)d_in[10];
  const float* bo = (const float*)d_in[11];

  const size_t MD = (size_t)16384 * 256;
  u16* qp  = (u16*)d_ws;
  u16* kp  = qp + MD;
  u16* vpt = kp + MD;                         // [4][256][4096]
  u16* ctx = vpt + MD;
  u16* wt  = ctx + MD;                        // 4 x 256x256 bf16
  float* ps   = (float*)(wt + 4 * 65536);     // [4][32][4096]
  float* ctxf = ps + (size_t)4 * 32 * 4096;   // [4 kg][4 b][4096][256] fp32 = 64MB
  u16* eb = (u16*)(ctxf + (size_t)16 * 1024 * 1024);  // packed tri [4][528][16384] bf16

  float* zout = (float*)d_out;
  float* attn = zout + (size_t)4 * 4096 * 256;

  k_wt<<<dim3(8, 8, 4), dim3(32, 8), 0, stream>>>(Wq, Wk, Wv, Wo, wt);
  k_pgemm3<<<dim3(2, 128, 3), 256, 0, stream>>>(q, k, v, wt, bq, bk, bv, qp, kp, vpt);
  k_qk<<<dim3(32, 32, 4), 256, 0, stream>>>(qp, kp, eb, attn, ps);
  k_pv2<<<dim3(4, 32, 4), 512, 0, stream>>>(eb, vpt, ps, attn, ctxf);
  k_cvt<<<4096, 256, 0, stream>>>(ctxf, ctx);
  k_gemm<false><<<dim3(2, 128), 256, 0, stream>>>(ctx, wt + 3 * 65536, bo, zout);
}

// Round 6
// 502.166 us; speedup vs baseline: 1.2199x; 1.1862x over previous
//
#include <hip/hip_runtime.h>

// OneHeadAttention: B=4, S=4096, D=256.
// out = [z (4*4096*256 fp32) | attn (4*4096*4096 fp32)]
//
// Pipeline:
//  k_wt      : W* fp32 [k][n] -> bf16 Wt [n][k]
//  k_pgemm3  : q,k,v fp32 -> (convert in-kernel) @ Wt + b -> qp,kp bf16; v-path
//              epilogue transposes -> vpt [b][n][s] bf16  (one launch, grid.z=3)
//  k_qk      : E = exp(qp kp^T/16) causal; lower tiles -> eb bf16 (packed
//              triangular tile layout); masked tiles -> attn zeros (nt);
//              ps row-sum partials.  XCD-chunked swizzle.
//  k_pv2     : split-K (balanced chunks) x n-split. LDS double-buffered
//              64-k half-steps, REG-STAGED: linear global_load_dwordx4 -> regs,
//              ds_write_b128 at XOR-swizzled LDS addr (byte col ^= (row&7)<<4).
//              Normalize phase reads A from LDS -> attn fp32 (nt). MFMA raw
//              E @ V; inv applied in epilogue; plain stores to per-kg ctxf
//              slice. One barrier per half-step; loads for step h+1 issued
//              before compute of step h (latency hidden under MFMA).
//  k_cvt     : sum written ctxf slices (chunk predicate) -> bf16 ctx
//  k_gemm    : z = ctx @ Wo + bo

typedef unsigned short u16;
typedef __attribute__((ext_vector_type(8))) short short8;
typedef __attribute__((ext_vector_type(4))) float f32x4;

struct __align__(8) us4 { u16 x, y, z, w; };

#define SEQ 4096
#define DIM 256

__device__ __forceinline__ u16 f2bf(float f) {
  unsigned int u = __float_as_uint(f);
  u += 0x7fffu + ((u >> 16) & 1u);
  return (u16)(u >> 16);
}
__device__ __forceinline__ float bf2f(u16 u) {
  return __uint_as_float(((unsigned int)u) << 16);
}

__device__ __forceinline__ void cp16(const void* g, void* l) {
  __builtin_amdgcn_global_load_lds((const __attribute__((address_space(1))) void*)g,
                                   (__attribute__((address_space(3))) void*)l, 16, 0, 0);
}

// ---------------- weight transpose ----------------
__global__ void k_wt(const float* __restrict__ Wq, const float* __restrict__ Wk,
                     const float* __restrict__ Wv, const float* __restrict__ Wo,
                     u16* __restrict__ wt) {
  __shared__ float t[32][33];
  const float* W = blockIdx.z == 0 ? Wq : blockIdx.z == 1 ? Wk : blockIdx.z == 2 ? Wv : Wo;
  u16* out = wt + (size_t)blockIdx.z * 65536;
  int n0 = blockIdx.x * 32, k0 = blockIdx.y * 32;
  int tx = threadIdx.x, ty = threadIdx.y;
  for (int i = 0; i < 4; i++)
    t[ty + i * 8][tx] = W[(size_t)(k0 + ty + i * 8) * 256 + n0 + tx];
  __syncthreads();
  for (int i = 0; i < 4; i++)
    out[(size_t)(n0 + ty + i * 8) * 256 + k0 + tx] = f2bf(t[tx][ty + i * 8]);
}

// ---------------- projection GEMMs, merged: z=0 -> qp, z=1 -> kp, z=2 -> vpt --
__global__ void k_pgemm3(const float* __restrict__ qin, const float* __restrict__ kin,
                         const float* __restrict__ vin, const u16* __restrict__ wtall,
                         const float* __restrict__ bq, const float* __restrict__ bk,
                         const float* __restrict__ bv,
                         u16* __restrict__ qp, u16* __restrict__ kp,
                         u16* __restrict__ vpt) {
  __shared__ __align__(16) char smem[34816];  // staging 16KB | TRANS epi 34816B
  const int z = blockIdx.z;
  const float* A = z == 0 ? qin : z == 1 ? kin : vin;
  const u16* Wt = wtall + (size_t)z * 65536;
  const float* bias = z == 0 ? bq : z == 1 ? bk : bv;
  u16* outp = z == 0 ? qp : z == 1 ? kp : vpt;
  const bool TRANS = (z == 2);

  u16* Asm = (u16*)smem;
  u16* Bsm = Asm + 4096;
  u16* tb = (u16*)smem;
  const int tid = threadIdx.x;
  const int lane = tid & 63, w = tid >> 6;
  const int wr = w >> 1, wc = w & 1;
  const int quad = lane >> 4, m16 = lane & 15;
  const int m0 = blockIdx.y * 128, n0 = blockIdx.x * 128;

  f32x4 zero = {0.f, 0.f, 0.f, 0.f};
  f32x4 acc[4][4];
  for (int i = 0; i < 4; i++)
    for (int j = 0; j < 4; j++) acc[i][j] = zero;

  for (int kk = 0; kk < 8; ++kk) {
    const int k0 = kk * 32;
    for (int h = 0; h < 2; ++h) {
      int c = tid + h * 256;
      int row = c >> 2, sub = c & 3;
      cp16(Wt + (size_t)(n0 + row) * 256 + k0 + sub * 8, Bsm + c * 8);
    }
    for (int h = 0; h < 4; ++h) {
      int idx = h * 256 + tid;
      int row = idx >> 3, q4 = idx & 7;
      float4 a4 = *(const float4*)(A + (size_t)(m0 + row) * 256 + k0 + q4 * 4);
      us4 o;
      o.x = f2bf(a4.x); o.y = f2bf(a4.y); o.z = f2bf(a4.z); o.w = f2bf(a4.w);
      *(us4*)(Asm + row * 32 + q4 * 4) = o;
    }
    __syncthreads();
    short8 a[4], b[4];
    for (int i = 0; i < 4; ++i)
      a[i] = *(const short8*)(Asm + (wr * 64 + i * 16 + m16) * 32 + quad * 8);
    for (int j = 0; j < 4; ++j)
      b[j] = *(const short8*)(Bsm + (wc * 64 + j * 16 + m16) * 32 + quad * 8);
    for (int i = 0; i < 4; ++i)
      for (int j = 0; j < 4; ++j)
        acc[i][j] = __builtin_amdgcn_mfma_f32_16x16x32_bf16(a[i], b[j], acc[i][j], 0, 0, 0);
    __syncthreads();
  }

  if (!TRANS) {
    for (int j = 0; j < 4; ++j) {
      int gn = n0 + wc * 64 + j * 16 + m16;
      float bvx = bias[gn];
      for (int i = 0; i < 4; ++i) {
        int gm = m0 + wr * 64 + i * 16 + quad * 4;
        for (int r = 0; r < 4; ++r)
          outp[(size_t)(gm + r) * 256 + gn] = f2bf(acc[i][j][r] + bvx);
      }
    }
  } else {
    // transpose epilogue -> vpt[b][n][s]
    for (int j = 0; j < 4; ++j) {
      int cn = wc * 64 + j * 16 + m16;
      float bvx = bias[n0 + cn];
      for (int i = 0; i < 4; ++i) {
        int rm = wr * 64 + i * 16 + quad * 4;
        us4 o;
        o.x = f2bf(acc[i][j][0] + bvx); o.y = f2bf(acc[i][j][1] + bvx);
        o.z = f2bf(acc[i][j][2] + bvx); o.w = f2bf(acc[i][j][3] + bvx);
        *(us4*)(tb + cn * 136 + rm) = o;
      }
    }
    __syncthreads();
    int b = m0 >> 12, s0 = m0 & 4095;
    u16* dst = outp + ((size_t)b << 20);
    for (int it = 0; it < 8; ++it) {
      int idx = it * 256 + tid;
      int n = idx >> 4, m8 = idx & 15;
      short8 v8 = *(const short8*)(tb + n * 136 + m8 * 8);
      *(short8*)(dst + (size_t)(n0 + n) * 4096 + s0 + m8 * 8) = v8;
    }
  }
}

// ---------------- QK^T, exp, causal ----------------------------------------
// eb is PACKED triangular: tile (qt,kt), kt<=qt, at index qt*(qt+1)/2+kt,
// each tile 128x128 bf16 contiguous (32KB).  XCD-chunked swizzle on work id.
__global__ void k_qk(const u16* __restrict__ qp, const u16* __restrict__ kp,
                     u16* __restrict__ eb, float* __restrict__ attn,
                     float* __restrict__ ps) {
  // bijective XCD swizzle: 4096 blocks, 8 XCDs -> each XCD a contiguous chunk
  int lin = blockIdx.x + (blockIdx.y << 5) + (blockIdx.z << 10);
  int wid = (lin & 7) * 512 + (lin >> 3);
  const int kt = wid & 31, qt = (wid >> 5) & 31, bz = wid >> 10;
  const int tid = threadIdx.x;
  const int q0 = qt * 128, k0t = kt * 128;

  if (kt > qt) {  // fully masked: attn zeros only
    float* attnb = attn + ((size_t)bz << 24);
    f32x4 z4 = {0.f, 0.f, 0.f, 0.f};
    for (int s = 0; s < 16; ++s) {
      int idx = tid + s * 256;
      int row = idx >> 5, c4 = idx & 31;
      __builtin_nontemporal_store(z4,
          (f32x4*)(attnb + (size_t)(q0 + row) * 4096 + k0t + c4 * 4));
    }
    return;
  }

  __shared__ __align__(16) char smem[34816];  // staging 16KB | epi u16 128x136
  u16* Asm = (u16*)smem;
  u16* Bsm = Asm + 4096;
  u16* epi = (u16*)smem;
  __shared__ float prow[2][128];

  const int lane = tid & 63, w = tid >> 6;
  const int wr = w >> 1, wc = w & 1;
  const int quad = lane >> 4, m16 = lane & 15;
  const u16* Ab = qp + ((size_t)bz << 20);
  const u16* Bb = kp + ((size_t)bz << 20);

  f32x4 zero = {0.f, 0.f, 0.f, 0.f};
  f32x4 acc[4][4];
  for (int i = 0; i < 4; i++)
    for (int j = 0; j < 4; j++) acc[i][j] = zero;

  for (int kk = 0; kk < 8; ++kk) {
    const int k0 = kk * 32;
    for (int h = 0; h < 2; ++h) {
      int c = tid + h * 256;
      int row = c >> 2, sub = c & 3;
      cp16(Ab + (size_t)(q0 + row) * 256 + k0 + sub * 8, Asm + c * 8);
      cp16(Bb + (size_t)(k0t + row) * 256 + k0 + sub * 8, Bsm + c * 8);
    }
    __syncthreads();
    short8 a[4], b[4];
    for (int i = 0; i < 4; ++i)
      a[i] = *(const short8*)(Asm + (wr * 64 + i * 16 + m16) * 32 + quad * 8);
    for (int j = 0; j < 4; ++j)
      b[j] = *(const short8*)(Bsm + (wc * 64 + j * 16 + m16) * 32 + quad * 8);
    for (int i = 0; i < 4; ++i)
      for (int j = 0; j < 4; ++j)
        acc[i][j] = __builtin_amdgcn_mfma_f32_16x16x32_bf16(a[i], b[j], acc[i][j], 0, 0, 0);
    __syncthreads();
  }

  // exp + causal mask + row-sum partials
  float rs[4][4];
  for (int i = 0; i < 4; i++)
    for (int r = 0; r < 4; r++) rs[i][r] = 0.f;
  for (int i = 0; i < 4; ++i) {
    int gq = q0 + wr * 64 + i * 16 + quad * 4;
    for (int j = 0; j < 4; ++j) {
      int gk = k0t + wc * 64 + j * 16 + m16;
      for (int r = 0; r < 4; ++r) {
        float e = (gk <= gq + r) ? __expf(acc[i][j][r] * 0.0625f) : 0.f;
        acc[i][j][r] = e;
        rs[i][r] += e;
      }
    }
  }
  for (int off = 1; off < 16; off <<= 1)
    for (int i = 0; i < 4; ++i)
      for (int r = 0; r < 4; ++r) rs[i][r] += __shfl_xor(rs[i][r], off, 64);
  if (m16 == 0)
    for (int i = 0; i < 4; ++i)
      for (int r = 0; r < 4; ++r)
        prow[wc][wr * 64 + i * 16 + quad * 4 + r] = rs[i][r];

  // dump E bf16 into LDS, then coalesced 16B nt stores to packed eb tile
  for (int i = 0; i < 4; ++i)
    for (int j = 0; j < 4; ++j) {
      int rl = wr * 64 + i * 16 + quad * 4;
      int cl = wc * 64 + j * 16 + m16;
      for (int r = 0; r < 4; ++r) epi[(rl + r) * 136 + cl] = f2bf(acc[i][j][r]);
    }
  __syncthreads();

  u16* ebt = eb + ((size_t)bz * 528 + (size_t)(qt * (qt + 1) / 2 + kt)) * 16384;
  for (int it = 0; it < 8; ++it) {
    int idx = it * 256 + tid;
    int row = idx >> 4, m8 = idx & 15;
    short8 v8 = *(const short8*)(epi + row * 136 + m8 * 8);
    __builtin_nontemporal_store(v8, (short8*)(ebt + row * 128 + m8 * 8));
  }
  if (tid < 128)
    ps[(size_t)(bz * 32 + kt) * 4096 + q0 + tid] = prow[0][tid] + prow[1][tid];
}

// ---------------- split-K PV, LDS double-buffered half-steps ----------------
// grid x: kg(4) x nh(2); balanced kg chunk = [kg*(qt+1)/4, (kg+1)*(qt+1)/4).
// A = raw eb tile rows (128q x 64k per half), B = vpt n-half (128n x 64k).
// REG-STAGED: linear coalesced global loads -> regs; ds_write_b128 to
// swizzled LDS addr (byte col ^= (row&7)<<4); reads apply same XOR.
__global__ void __launch_bounds__(512) k_pv2(const u16* __restrict__ eb,
                                             const u16* __restrict__ vpt,
                                             const float* __restrict__ ps,
                                             float* __restrict__ attn,
                                             float* __restrict__ ctxf) {
  // bijective XCD swizzle over 1024 blocks
  int lin = blockIdx.x + (blockIdx.y << 3) + (blockIdx.z << 8);
  int wid = (lin & 7) * 128 + (lin >> 3);
  const int nh = wid & 1, kg = (wid >> 1) & 3;
  const int qt = (wid >> 3) & 31, bz = wid >> 8;
  const int nt_lo = (kg * (qt + 1)) >> 2;
  const int nt_hi = ((kg + 1) * (qt + 1)) >> 2;
  if (nt_lo >= nt_hi) return;

  __shared__ u16 A_lds[2][128 * 64];   // 2 x 16KB
  __shared__ u16 B_lds[2][128 * 64];   // 2 x 16KB
  __shared__ float inv_lds[128];

  const int tid = threadIdx.x;
  const int lane = tid & 63, w = tid >> 6;
  const int wr = w >> 2, wc = w & 3;     // wr: q-half(64), wc: n-32-quarter
  const int quad = lane >> 4, m16 = lane & 15;
  const int q0 = qt * 128;
  const u16* ebq = eb + ((size_t)bz * 528 + (size_t)(qt * (qt + 1) / 2)) * 16384;
  float* attnb = attn + ((size_t)bz << 24);
  const u16* vb = vpt + ((size_t)bz << 20) + (size_t)nh * 128 * 4096;

  if (tid < 128) {
    float s = 0.f;
    for (int kt = 0; kt <= qt; ++kt)
      s += ps[(size_t)(bz * 32 + kt) * 4096 + q0 + tid];
    inv_lds[tid] = 1.f / s;
  }

  // staging registers (2 chunks of 16B each for A and B per thread)
  short8 arg0, arg1, brg0, brg1;
  const int srow0 = tid >> 3, srow1 = (512 + tid) >> 3;  // rows for t=0,1
  const int sc = tid & 7;                                 // 16B chunk in row

  auto stage_load = [&](int hh) {
    int t0 = nt_lo + (hh >> 1), h = hh & 1;
    const u16* tile = ebq + (size_t)t0 * 16384 + h * 64;
    int kt0 = t0 * 128 + h * 64;
    arg0 = *(const short8*)(tile + srow0 * 128 + sc * 8);
    arg1 = *(const short8*)(tile + srow1 * 128 + sc * 8);
    brg0 = *(const short8*)(vb + (size_t)srow0 * 4096 + kt0 + sc * 8);
    brg1 = *(const short8*)(vb + (size_t)srow1 * 4096 + kt0 + sc * 8);
  };
  const int soff0 = srow0 * 64 + ((((sc << 4) ^ ((srow0 & 7) << 4))) >> 1);
  const int soff1 = srow1 * 64 + ((((sc << 4) ^ ((srow1 & 7) << 4))) >> 1);
  auto stage_write = [&](int buf) {
    *(short8*)(A_lds[buf] + soff0) = arg0;
    *(short8*)(A_lds[buf] + soff1) = arg1;
    *(short8*)(B_lds[buf] + soff0) = brg0;
    *(short8*)(B_lds[buf] + soff1) = brg1;
  };

  const int khalves = (nt_hi - nt_lo) * 2;
  stage_load(0);
  stage_write(0);
  __syncthreads();

  f32x4 zero = {0.f, 0.f, 0.f, 0.f};
  f32x4 acc[4][2];
  for (int i = 0; i < 4; i++)
    for (int j = 0; j < 2; j++) acc[i][j] = zero;

  for (int hh = 0; hh < khalves; ++hh) {
    const int buf = hh & 1;
    if (hh + 1 < khalves) stage_load(hh + 1);  // latency hidden under compute

    // normalize own 64 rows of this half -> attn fp32 (nt), 1 chunk/thread
    {
      int rl = nh * 64 + (tid >> 3);
      int c8 = tid & 7;
      int lb = rl * 64 + ((((c8 << 4) ^ ((rl & 7) << 4))) >> 1);
      short8 e8 = *(const short8*)(A_lds[buf] + lb);
      float ivr = inv_lds[rl];
      f32x4 lo, hi;
      for (int t = 0; t < 4; ++t) lo[t] = bf2f((u16)e8[t]) * ivr;
      for (int t = 0; t < 4; ++t) hi[t] = bf2f((u16)e8[t + 4]) * ivr;
      int kcol = (nt_lo + (hh >> 1)) * 128 + (hh & 1) * 64 + (c8 << 3);
      float* dst = attnb + (size_t)(q0 + rl) * 4096 + kcol;
      __builtin_nontemporal_store(lo, (f32x4*)dst);
      __builtin_nontemporal_store(hi, (f32x4*)(dst + 4));
    }

    // MFMA over the 64-k half (2 x 32k steps)
    for (int ks = 0; ks < 2; ++ks) {
      short8 a[4], b[2];
      for (int i = 0; i < 4; ++i) {
        int row = wr * 64 + i * 16 + m16;
        int xb = (ks * 64 + quad * 16) ^ ((row & 7) << 4);
        a[i] = *(const short8*)(A_lds[buf] + row * 64 + (xb >> 1));
      }
      for (int j = 0; j < 2; ++j) {
        int n = wc * 32 + j * 16 + m16;
        int xb = (ks * 64 + quad * 16) ^ ((n & 7) << 4);
        b[j] = *(const short8*)(B_lds[buf] + n * 64 + (xb >> 1));
      }
      for (int i = 0; i < 4; ++i)
        for (int j = 0; j < 2; ++j)
          acc[i][j] = __builtin_amdgcn_mfma_f32_16x16x32_bf16(a[i], b[j], acc[i][j], 0, 0, 0);
    }

    if (hh + 1 < khalves) stage_write(buf ^ 1);  // WAR-safe: buf^1 readers done
    __syncthreads();  // writes visible before next iter reads buf^1
  }

  // epilogue: scale by inv, plain coalesced stores to this kg's private slice
  float* ctxs = ctxf + ((size_t)(kg * 4 + bz) << 20);
  for (int i = 0; i < 4; ++i) {
    int rl = wr * 64 + i * 16 + quad * 4;
    for (int j = 0; j < 2; ++j) {
      int gn = nh * 128 + wc * 32 + j * 16 + m16;
      for (int r = 0; r < 4; ++r)
        ctxs[(size_t)(q0 + rl + r) * 256 + gn] = acc[i][j][r] * inv_lds[rl + r];
    }
  }
}

// ---------------- sum written ctxf slices -> bf16 ctx ----------------
__global__ void k_cvt(const float* __restrict__ ctxf, u16* __restrict__ ctx) {
  size_t i4 = (size_t)blockIdx.x * 256 + threadIdx.x;  // float4 index over [4][4096][64]
  int bz = (int)(i4 >> 18);
  size_t rem4 = i4 & (((size_t)1 << 18) - 1);
  int qrow = (int)(rem4 >> 6);
  int qt = qrow >> 7;
  const float4* base = (const float4*)ctxf;
  float4 s = make_float4(0.f, 0.f, 0.f, 0.f);
  for (int kg = 0; kg < 4; ++kg) {
    if ((((kg + 1) * (qt + 1)) >> 2) > ((kg * (qt + 1)) >> 2)) {
      float4 t = base[((size_t)(kg * 4 + bz) << 18) + rem4];
      s.x += t.x; s.y += t.y; s.z += t.z; s.w += t.w;
    }
  }
  us4 o;
  o.x = f2bf(s.x); o.y = f2bf(s.y); o.z = f2bf(s.z); o.w = f2bf(s.w);
  ((us4*)ctx)[i4] = o;
}

// ---------------- bf16-input GEMM (final projection) ----------------
template <bool OUT_BF16>
__global__ void k_gemm(const u16* __restrict__ A, const u16* __restrict__ Wt,
                       const float* __restrict__ bias, void* __restrict__ outp) {
  __shared__ u16 Asm[128 * 32];
  __shared__ u16 Bsm[128 * 32];
  const int tid = threadIdx.x;
  const int lane = tid & 63, w = tid >> 6;
  const int wr = w >> 1, wc = w & 1;
  const int quad = lane >> 4, m16 = lane & 15;
  const int m0 = blockIdx.y * 128, n0 = blockIdx.x * 128;

  f32x4 zero = {0.f, 0.f, 0.f, 0.f};
  f32x4 acc[4][4];
  for (int i = 0; i < 4; i++)
    for (int j = 0; j < 4; j++) acc[i][j] = zero;

  for (int kk = 0; kk < 8; ++kk) {
    const int k0 = kk * 32;
    for (int h = 0; h < 2; ++h) {
      int c = tid + h * 256;
      int row = c >> 2, sub = c & 3;
      cp16(A + (size_t)(m0 + row) * 256 + k0 + sub * 8, Asm + c * 8);
      cp16(Wt + (size_t)(n0 + row) * 256 + k0 + sub * 8, Bsm + c * 8);
    }
    __syncthreads();
    short8 a[4], b[4];
    for (int i = 0; i < 4; ++i)
      a[i] = *(const short8*)(Asm + (wr * 64 + i * 16 + m16) * 32 + quad * 8);
    for (int j = 0; j < 4; ++j)
      b[j] = *(const short8*)(Bsm + (wc * 64 + j * 16 + m16) * 32 + quad * 8);
    for (int i = 0; i < 4; ++i)
      for (int j = 0; j < 4; ++j)
        acc[i][j] = __builtin_amdgcn_mfma_f32_16x16x32_bf16(a[i], b[j], acc[i][j], 0, 0, 0);
    __syncthreads();
  }

  for (int j = 0; j < 4; ++j) {
    int gn = n0 + wc * 64 + j * 16 + m16;
    float bv = bias[gn];
    for (int i = 0; i < 4; ++i) {
      int gm = m0 + wr * 64 + i * 16 + quad * 4;
      for (int r = 0; r < 4; ++r) {
        float val = acc[i][j][r] + bv;
        if (OUT_BF16)
          ((u16*)outp)[(size_t)(gm + r) * 256 + gn] = f2bf(val);
        else
          ((float*)outp)[(size_t)(gm + r) * 256 + gn] = val;
      }
    }
  }
}

extern "C" void kernel_launch(void* const* d_in, const int* in_sizes, int n_in,
                              void* d_out, int out_size, void* d_ws, size_t ws_size,
                              hipStream_t stream) {
  const float* q  = (const float*)d_in[0];
  const float* k  = (const float*)d_in[1];
  const float* v  = (const float*)d_in[2];
  const float* Wq = (const float*)d_in[4];
  const float* bq = (const float*)d_in[5];
  const float* Wk = (const float*)d_in[6];
  const float* bk = (const float*)d_in[7];
  const float* Wv = (const float*)d_in[8];
  const float* bv = (const float*)d_in[9];
  const float* Wo = (const float*)d_in[10];
  const float* bo = (const float*)d_in[11];

  const size_t MD = (size_t)16384 * 256;
  u16* qp  = (u16*)d_ws;
  u16* kp  = qp + MD;
  u16* vpt = kp + MD;                         // [4][256][4096]
  u16* ctx = vpt + MD;
  u16* wt  = ctx + MD;                        // 4 x 256x256 bf16
  float* ps   = (float*)(wt + 4 * 65536);     // [4][32][4096]
  float* ctxf = ps + (size_t)4 * 32 * 4096;   // [4 kg][4 b][4096][256] fp32 = 64MB
  u16* eb = (u16*)(ctxf + (size_t)16 * 1024 * 1024);  // packed tri [4][528][16384] bf16

  float* zout = (float*)d_out;
  float* attn = zout + (size_t)4 * 4096 * 256;

  k_wt<<<dim3(8, 8, 4), dim3(32, 8), 0, stream>>>(Wq, Wk, Wv, Wo, wt);
  k_pgemm3<<<dim3(2, 128, 3), 256, 0, stream>>>(q, k, v, wt, bq, bk, bv, qp, kp, vpt);
  k_qk<<<dim3(32, 32, 4), 256, 0, stream>>>(qp, kp, eb, attn, ps);
  k_pv2<<<dim3(8, 32, 4), 512, 0, stream>>>(eb, vpt, ps, attn, ctxf);
  k_cvt<<<4096, 256, 0, stream>>>(ctxf, ctx);
  k_gemm<false><<<dim3(2, 128), 256, 0, stream>>>(ctx, wt + 3 * 65536, bo, zout);
}

// Round 7
// 494.159 us; speedup vs baseline: 1.2397x; 1.0162x over previous
//
#include <hip/hip_runtime.h>

// OneHeadAttention: B=4, S=4096, D=256.
// out = [z (4*4096*256 fp32) | attn (4*4096*4096 fp32)]
//
// Pipeline:
//  k_wt      : W* fp32 [k][n] -> bf16 Wt [n][k]
//  k_pgemm3  : q,k,v fp32 -> @ Wt + b -> qp,kp bf16; v-path transposed -> vpt
//  k_qk      : E = exp(qp kp^T/16) causal; lower tiles -> eb bf16 (packed
//              triangular, PLAIN stores so eb stays L2/L3-resident for pv2);
//              masked tiles -> attn zeros (nt); ps row-sum partials.
//  k_pv2     : split-K (balanced chunks) x n-split. 256-thread blocks, 4 warps
//              in 2x2 -> 64q x 64n per warp (square tiles minimize LDS reads
//              per MFMA: a[4]+b[4] feed 16 MFMAs). LDS double-buffered 64-k
//              half-steps, reg-staged with XOR-swizzled ds_write. Normalize
//              reads A from LDS -> attn fp32 (nt). inv applied in epilogue;
//              plain stores to per-kg ctxf slice.
//  k_cvt     : sum written ctxf slices (chunk predicate) -> bf16 ctx
//  k_gemm    : z = ctx @ Wo + bo

typedef unsigned short u16;
typedef __attribute__((ext_vector_type(8))) short short8;
typedef __attribute__((ext_vector_type(4))) float f32x4;

struct __align__(8) us4 { u16 x, y, z, w; };

#define SEQ 4096
#define DIM 256

__device__ __forceinline__ u16 f2bf(float f) {
  unsigned int u = __float_as_uint(f);
  u += 0x7fffu + ((u >> 16) & 1u);
  return (u16)(u >> 16);
}
__device__ __forceinline__ float bf2f(u16 u) {
  return __uint_as_float(((unsigned int)u) << 16);
}

__device__ __forceinline__ void cp16(const void* g, void* l) {
  __builtin_amdgcn_global_load_lds((const __attribute__((address_space(1))) void*)g,
                                   (__attribute__((address_space(3))) void*)l, 16, 0, 0);
}

// ---------------- weight transpose ----------------
__global__ void k_wt(const float* __restrict__ Wq, const float* __restrict__ Wk,
                     const float* __restrict__ Wv, const float* __restrict__ Wo,
                     u16* __restrict__ wt) {
  __shared__ float t[32][33];
  const float* W = blockIdx.z == 0 ? Wq : blockIdx.z == 1 ? Wk : blockIdx.z == 2 ? Wv : Wo;
  u16* out = wt + (size_t)blockIdx.z * 65536;
  int n0 = blockIdx.x * 32, k0 = blockIdx.y * 32;
  int tx = threadIdx.x, ty = threadIdx.y;
  for (int i = 0; i < 4; i++)
    t[ty + i * 8][tx] = W[(size_t)(k0 + ty + i * 8) * 256 + n0 + tx];
  __syncthreads();
  for (int i = 0; i < 4; i++)
    out[(size_t)(n0 + ty + i * 8) * 256 + k0 + tx] = f2bf(t[tx][ty + i * 8]);
}

// ---------------- projection GEMMs, merged: z=0 -> qp, z=1 -> kp, z=2 -> vpt --
__global__ void k_pgemm3(const float* __restrict__ qin, const float* __restrict__ kin,
                         const float* __restrict__ vin, const u16* __restrict__ wtall,
                         const float* __restrict__ bq, const float* __restrict__ bk,
                         const float* __restrict__ bv,
                         u16* __restrict__ qp, u16* __restrict__ kp,
                         u16* __restrict__ vpt) {
  __shared__ __align__(16) char smem[34816];  // staging 16KB | TRANS epi 34816B
  const int z = blockIdx.z;
  const float* A = z == 0 ? qin : z == 1 ? kin : vin;
  const u16* Wt = wtall + (size_t)z * 65536;
  const float* bias = z == 0 ? bq : z == 1 ? bk : bv;
  u16* outp = z == 0 ? qp : z == 1 ? kp : vpt;
  const bool TRANS = (z == 2);

  u16* Asm = (u16*)smem;
  u16* Bsm = Asm + 4096;
  u16* tb = (u16*)smem;
  const int tid = threadIdx.x;
  const int lane = tid & 63, w = tid >> 6;
  const int wr = w >> 1, wc = w & 1;
  const int quad = lane >> 4, m16 = lane & 15;
  const int m0 = blockIdx.y * 128, n0 = blockIdx.x * 128;

  f32x4 zero = {0.f, 0.f, 0.f, 0.f};
  f32x4 acc[4][4];
  for (int i = 0; i < 4; i++)
    for (int j = 0; j < 4; j++) acc[i][j] = zero;

  for (int kk = 0; kk < 8; ++kk) {
    const int k0 = kk * 32;
    for (int h = 0; h < 2; ++h) {
      int c = tid + h * 256;
      int row = c >> 2, sub = c & 3;
      cp16(Wt + (size_t)(n0 + row) * 256 + k0 + sub * 8, Bsm + c * 8);
    }
    for (int h = 0; h < 4; ++h) {
      int idx = h * 256 + tid;
      int row = idx >> 3, q4 = idx & 7;
      float4 a4 = *(const float4*)(A + (size_t)(m0 + row) * 256 + k0 + q4 * 4);
      us4 o;
      o.x = f2bf(a4.x); o.y = f2bf(a4.y); o.z = f2bf(a4.z); o.w = f2bf(a4.w);
      *(us4*)(Asm + row * 32 + q4 * 4) = o;
    }
    __syncthreads();
    short8 a[4], b[4];
    for (int i = 0; i < 4; ++i)
      a[i] = *(const short8*)(Asm + (wr * 64 + i * 16 + m16) * 32 + quad * 8);
    for (int j = 0; j < 4; ++j)
      b[j] = *(const short8*)(Bsm + (wc * 64 + j * 16 + m16) * 32 + quad * 8);
    for (int i = 0; i < 4; ++i)
      for (int j = 0; j < 4; ++j)
        acc[i][j] = __builtin_amdgcn_mfma_f32_16x16x32_bf16(a[i], b[j], acc[i][j], 0, 0, 0);
    __syncthreads();
  }

  if (!TRANS) {
    for (int j = 0; j < 4; ++j) {
      int gn = n0 + wc * 64 + j * 16 + m16;
      float bvx = bias[gn];
      for (int i = 0; i < 4; ++i) {
        int gm = m0 + wr * 64 + i * 16 + quad * 4;
        for (int r = 0; r < 4; ++r)
          outp[(size_t)(gm + r) * 256 + gn] = f2bf(acc[i][j][r] + bvx);
      }
    }
  } else {
    // transpose epilogue -> vpt[b][n][s]
    for (int j = 0; j < 4; ++j) {
      int cn = wc * 64 + j * 16 + m16;
      float bvx = bias[n0 + cn];
      for (int i = 0; i < 4; ++i) {
        int rm = wr * 64 + i * 16 + quad * 4;
        us4 o;
        o.x = f2bf(acc[i][j][0] + bvx); o.y = f2bf(acc[i][j][1] + bvx);
        o.z = f2bf(acc[i][j][2] + bvx); o.w = f2bf(acc[i][j][3] + bvx);
        *(us4*)(tb + cn * 136 + rm) = o;
      }
    }
    __syncthreads();
    int b = m0 >> 12, s0 = m0 & 4095;
    u16* dst = outp + ((size_t)b << 20);
    for (int it = 0; it < 8; ++it) {
      int idx = it * 256 + tid;
      int n = idx >> 4, m8 = idx & 15;
      short8 v8 = *(const short8*)(tb + n * 136 + m8 * 8);
      *(short8*)(dst + (size_t)(n0 + n) * 4096 + s0 + m8 * 8) = v8;
    }
  }
}

// ---------------- QK^T, exp, causal ----------------------------------------
// eb is PACKED triangular: tile (qt,kt), kt<=qt, at index qt*(qt+1)/2+kt,
// each tile 128x128 bf16 contiguous (32KB).  XCD-chunked swizzle on work id.
__global__ void k_qk(const u16* __restrict__ qp, const u16* __restrict__ kp,
                     u16* __restrict__ eb, float* __restrict__ attn,
                     float* __restrict__ ps) {
  // bijective XCD swizzle: 4096 blocks, 8 XCDs -> each XCD a contiguous chunk
  int lin = blockIdx.x + (blockIdx.y << 5) + (blockIdx.z << 10);
  int wid = (lin & 7) * 512 + (lin >> 3);
  const int kt = wid & 31, qt = (wid >> 5) & 31, bz = wid >> 10;
  const int tid = threadIdx.x;
  const int q0 = qt * 128, k0t = kt * 128;

  if (kt > qt) {  // fully masked: attn zeros only
    float* attnb = attn + ((size_t)bz << 24);
    f32x4 z4 = {0.f, 0.f, 0.f, 0.f};
    for (int s = 0; s < 16; ++s) {
      int idx = tid + s * 256;
      int row = idx >> 5, c4 = idx & 31;
      __builtin_nontemporal_store(z4,
          (f32x4*)(attnb + (size_t)(q0 + row) * 4096 + k0t + c4 * 4));
    }
    return;
  }

  __shared__ __align__(16) char smem[34816];  // staging 16KB | epi u16 128x136
  u16* Asm = (u16*)smem;
  u16* Bsm = Asm + 4096;
  u16* epi = (u16*)smem;
  __shared__ float prow[2][128];

  const int lane = tid & 63, w = tid >> 6;
  const int wr = w >> 1, wc = w & 1;
  const int quad = lane >> 4, m16 = lane & 15;
  const u16* Ab = qp + ((size_t)bz << 20);
  const u16* Bb = kp + ((size_t)bz << 20);

  f32x4 zero = {0.f, 0.f, 0.f, 0.f};
  f32x4 acc[4][4];
  for (int i = 0; i < 4; i++)
    for (int j = 0; j < 4; j++) acc[i][j] = zero;

  for (int kk = 0; kk < 8; ++kk) {
    const int k0 = kk * 32;
    for (int h = 0; h < 2; ++h) {
      int c = tid + h * 256;
      int row = c >> 2, sub = c & 3;
      cp16(Ab + (size_t)(q0 + row) * 256 + k0 + sub * 8, Asm + c * 8);
      cp16(Bb + (size_t)(k0t + row) * 256 + k0 + sub * 8, Bsm + c * 8);
    }
    __syncthreads();
    short8 a[4], b[4];
    for (int i = 0; i < 4; ++i)
      a[i] = *(const short8*)(Asm + (wr * 64 + i * 16 + m16) * 32 + quad * 8);
    for (int j = 0; j < 4; ++j)
      b[j] = *(const short8*)(Bsm + (wc * 64 + j * 16 + m16) * 32 + quad * 8);
    for (int i = 0; i < 4; ++i)
      for (int j = 0; j < 4; ++j)
        acc[i][j] = __builtin_amdgcn_mfma_f32_16x16x32_bf16(a[i], b[j], acc[i][j], 0, 0, 0);
    __syncthreads();
  }

  // exp + causal mask + row-sum partials
  float rs[4][4];
  for (int i = 0; i < 4; i++)
    for (int r = 0; r < 4; r++) rs[i][r] = 0.f;
  for (int i = 0; i < 4; ++i) {
    int gq = q0 + wr * 64 + i * 16 + quad * 4;
    for (int j = 0; j < 4; ++j) {
      int gk = k0t + wc * 64 + j * 16 + m16;
      for (int r = 0; r < 4; ++r) {
        float e = (gk <= gq + r) ? __expf(acc[i][j][r] * 0.0625f) : 0.f;
        acc[i][j][r] = e;
        rs[i][r] += e;
      }
    }
  }
  for (int off = 1; off < 16; off <<= 1)
    for (int i = 0; i < 4; ++i)
      for (int r = 0; r < 4; ++r) rs[i][r] += __shfl_xor(rs[i][r], off, 64);
  if (m16 == 0)
    for (int i = 0; i < 4; ++i)
      for (int r = 0; r < 4; ++r)
        prow[wc][wr * 64 + i * 16 + quad * 4 + r] = rs[i][r];

  // dump E bf16 into LDS, then coalesced 16B PLAIN stores to packed eb tile
  // (plain so eb stays L2/L3-resident for pv2's reads)
  for (int i = 0; i < 4; ++i)
    for (int j = 0; j < 4; ++j) {
      int rl = wr * 64 + i * 16 + quad * 4;
      int cl = wc * 64 + j * 16 + m16;
      for (int r = 0; r < 4; ++r) epi[(rl + r) * 136 + cl] = f2bf(acc[i][j][r]);
    }
  __syncthreads();

  u16* ebt = eb + ((size_t)bz * 528 + (size_t)(qt * (qt + 1) / 2 + kt)) * 16384;
  for (int it = 0; it < 8; ++it) {
    int idx = it * 256 + tid;
    int row = idx >> 4, m8 = idx & 15;
    short8 v8 = *(const short8*)(epi + row * 136 + m8 * 8);
    *(short8*)(ebt + row * 128 + m8 * 8) = v8;
  }
  if (tid < 128)
    ps[(size_t)(bz * 32 + kt) * 4096 + q0 + tid] = prow[0][tid] + prow[1][tid];
}

// ---------------- split-K PV, LDS double-buffered half-steps ----------------
// grid x: kg(4) x nh(2); balanced kg chunk = [kg*(qt+1)/4, (kg+1)*(qt+1)/4).
// 256 threads, 4 warps in 2x2 -> 64q x 64n per warp (square tile: a[4]+b[4]
// reads feed 16 MFMAs -> minimal LDS traffic per MFMA).
// A = raw eb tile rows (128q x 64k per half), B = vpt n-half (128n x 64k).
// REG-STAGED: linear coalesced global loads -> regs; ds_write_b128 to
// swizzled LDS addr (byte col ^= (row&7)<<4); reads apply same XOR.
__global__ void __launch_bounds__(256) k_pv2(const u16* __restrict__ eb,
                                             const u16* __restrict__ vpt,
                                             const float* __restrict__ ps,
                                             float* __restrict__ attn,
                                             float* __restrict__ ctxf) {
  // bijective XCD swizzle over 1024 blocks
  int lin = blockIdx.x + (blockIdx.y << 3) + (blockIdx.z << 8);
  int wid = (lin & 7) * 128 + (lin >> 3);
  const int nh = wid & 1, kg = (wid >> 1) & 3;
  const int qt = (wid >> 3) & 31, bz = wid >> 8;
  const int nt_lo = (kg * (qt + 1)) >> 2;
  const int nt_hi = ((kg + 1) * (qt + 1)) >> 2;
  if (nt_lo >= nt_hi) return;

  __shared__ u16 A_lds[2][128 * 64];   // 2 x 16KB
  __shared__ u16 B_lds[2][128 * 64];   // 2 x 16KB
  __shared__ float inv_lds[128];

  const int tid = threadIdx.x;
  const int lane = tid & 63, w = tid >> 6;
  const int wr = w >> 1, wc = w & 1;     // 2x2 warps: 64q x 64n each
  const int quad = lane >> 4, m16 = lane & 15;
  const int q0 = qt * 128;
  const u16* ebq = eb + ((size_t)bz * 528 + (size_t)(qt * (qt + 1) / 2)) * 16384;
  float* attnb = attn + ((size_t)bz << 24);
  const u16* vb = vpt + ((size_t)bz << 20) + (size_t)nh * 128 * 4096;

  if (tid < 128) {
    float s = 0.f;
    for (int kt = 0; kt <= qt; ++kt)
      s += ps[(size_t)(bz * 32 + kt) * 4096 + q0 + tid];
    inv_lds[tid] = 1.f / s;
  }

  // staging registers: 4 chunks of 16B each for A and B per thread
  short8 arg[4], brg[4];
  const int sc = tid & 7;                 // 16B chunk in 128B row
  int srow[4], soff[4];
  for (int t = 0; t < 4; ++t) {
    srow[t] = (t * 256 + tid) >> 3;       // 0..127
    soff[t] = srow[t] * 64 + ((((sc << 4) ^ ((srow[t] & 7) << 4))) >> 1);
  }

  auto stage_load = [&](int hh) {
    int t0 = nt_lo + (hh >> 1), h = hh & 1;
    const u16* tile = ebq + (size_t)t0 * 16384 + h * 64;
    int kt0 = t0 * 128 + h * 64;
    for (int t = 0; t < 4; ++t) {
      arg[t] = *(const short8*)(tile + srow[t] * 128 + sc * 8);
      brg[t] = *(const short8*)(vb + (size_t)srow[t] * 4096 + kt0 + sc * 8);
    }
  };
  auto stage_write = [&](int buf) {
    for (int t = 0; t < 4; ++t) {
      *(short8*)(A_lds[buf] + soff[t]) = arg[t];
      *(short8*)(B_lds[buf] + soff[t]) = brg[t];
    }
  };

  const int khalves = (nt_hi - nt_lo) * 2;
  stage_load(0);
  stage_write(0);
  __syncthreads();

  f32x4 zero = {0.f, 0.f, 0.f, 0.f};
  f32x4 acc[4][4];
  for (int i = 0; i < 4; i++)
    for (int j = 0; j < 4; j++) acc[i][j] = zero;

  for (int hh = 0; hh < khalves; ++hh) {
    const int buf = hh & 1;
    if (hh + 1 < khalves) stage_load(hh + 1);  // latency hidden under compute

    // normalize this half's 128 rows -> attn fp32 (nt), 4 chunks/thread
    for (int p = 0; p < 4; ++p) {
      int idx = p * 256 + tid;
      int rl = idx >> 3, c8 = idx & 7;
      int lb = rl * 64 + ((((c8 << 4) ^ ((rl & 7) << 4))) >> 1);
      short8 e8 = *(const short8*)(A_lds[buf] + lb);
      float ivr = inv_lds[rl];
      f32x4 lo, hi;
      for (int t = 0; t < 4; ++t) lo[t] = bf2f((u16)e8[t]) * ivr;
      for (int t = 0; t < 4; ++t) hi[t] = bf2f((u16)e8[t + 4]) * ivr;
      int kcol = (nt_lo + (hh >> 1)) * 128 + (hh & 1) * 64 + (c8 << 3);
      float* dst = attnb + (size_t)(q0 + rl) * 4096 + kcol;
      __builtin_nontemporal_store(lo, (f32x4*)dst);
      __builtin_nontemporal_store(hi, (f32x4*)(dst + 4));
    }

    // MFMA over the 64-k half (2 x 32k steps), 16 MFMA per warp per ks
    for (int ks = 0; ks < 2; ++ks) {
      short8 a[4], b[4];
      for (int i = 0; i < 4; ++i) {
        int row = wr * 64 + i * 16 + m16;
        int xb = (ks * 64 + quad * 16) ^ ((row & 7) << 4);
        a[i] = *(const short8*)(A_lds[buf] + row * 64 + (xb >> 1));
      }
      for (int j = 0; j < 4; ++j) {
        int n = wc * 64 + j * 16 + m16;
        int xb = (ks * 64 + quad * 16) ^ ((n & 7) << 4);
        b[j] = *(const short8*)(B_lds[buf] + n * 64 + (xb >> 1));
      }
      for (int i = 0; i < 4; ++i)
        for (int j = 0; j < 4; ++j)
          acc[i][j] = __builtin_amdgcn_mfma_f32_16x16x32_bf16(a[i], b[j], acc[i][j], 0, 0, 0);
    }

    if (hh + 1 < khalves) stage_write(buf ^ 1);  // WAR-safe: buf^1 readers done
    __syncthreads();  // writes visible before next iter reads buf^1
  }

  // epilogue: scale by inv, plain coalesced stores to this kg's private slice
  float* ctxs = ctxf + ((size_t)(kg * 4 + bz) << 20);
  for (int i = 0; i < 4; ++i) {
    int rl = wr * 64 + i * 16 + quad * 4;
    for (int j = 0; j < 4; ++j) {
      int gn = nh * 128 + wc * 64 + j * 16 + m16;
      for (int r = 0; r < 4; ++r)
        ctxs[(size_t)(q0 + rl + r) * 256 + gn] = acc[i][j][r] * inv_lds[rl + r];
    }
  }
}

// ---------------- sum written ctxf slices -> bf16 ctx ----------------
__global__ void k_cvt(const float* __restrict__ ctxf, u16* __restrict__ ctx) {
  size_t i4 = (size_t)blockIdx.x * 256 + threadIdx.x;  // float4 index over [4][4096][64]
  int bz = (int)(i4 >> 18);
  size_t rem4 = i4 & (((size_t)1 << 18) - 1);
  int qrow = (int)(rem4 >> 6);
  int qt = qrow >> 7;
  const float4* base = (const float4*)ctxf;
  float4 s = make_float4(0.f, 0.f, 0.f, 0.f);
  for (int kg = 0; kg < 4; ++kg) {
    if ((((kg + 1) * (qt + 1)) >> 2) > ((kg * (qt + 1)) >> 2)) {
      float4 t = base[((size_t)(kg * 4 + bz) << 18) + rem4];
      s.x += t.x; s.y += t.y; s.z += t.z; s.w += t.w;
    }
  }
  us4 o;
  o.x = f2bf(s.x); o.y = f2bf(s.y); o.z = f2bf(s.z); o.w = f2bf(s.w);
  ((us4*)ctx)[i4] = o;
}

// ---------------- bf16-input GEMM (final projection) ----------------
template <bool OUT_BF16>
__global__ void k_gemm(const u16* __restrict__ A, const u16* __restrict__ Wt,
                       const float* __restrict__ bias, void* __restrict__ outp) {
  __shared__ u16 Asm[128 * 32];
  __shared__ u16 Bsm[128 * 32];
  const int tid = threadIdx.x;
  const int lane = tid & 63, w = tid >> 6;
  const int wr = w >> 1, wc = w & 1;
  const int quad = lane >> 4, m16 = lane & 15;
  const int m0 = blockIdx.y * 128, n0 = blockIdx.x * 128;

  f32x4 zero = {0.f, 0.f, 0.f, 0.f};
  f32x4 acc[4][4];
  for (int i = 0; i < 4; i++)
    for (int j = 0; j < 4; j++) acc[i][j] = zero;

  for (int kk = 0; kk < 8; ++kk) {
    const int k0 = kk * 32;
    for (int h = 0; h < 2; ++h) {
      int c = tid + h * 256;
      int row = c >> 2, sub = c & 3;
      cp16(A + (size_t)(m0 + row) * 256 + k0 + sub * 8, Asm + c * 8);
      cp16(Wt + (size_t)(n0 + row) * 256 + k0 + sub * 8, Bsm + c * 8);
    }
    __syncthreads();
    short8 a[4], b[4];
    for (int i = 0; i < 4; ++i)
      a[i] = *(const short8*)(Asm + (wr * 64 + i * 16 + m16) * 32 + quad * 8);
    for (int j = 0; j < 4; ++j)
      b[j] = *(const short8*)(Bsm + (wc * 64 + j * 16 + m16) * 32 + quad * 8);
    for (int i = 0; i < 4; ++i)
      for (int j = 0; j < 4; ++j)
        acc[i][j] = __builtin_amdgcn_mfma_f32_16x16x32_bf16(a[i], b[j], acc[i][j], 0, 0, 0);
    __syncthreads();
  }

  for (int j = 0; j < 4; ++j) {
    int gn = n0 + wc * 64 + j * 16 + m16;
    float bv = bias[gn];
    for (int i = 0; i < 4; ++i) {
      int gm = m0 + wr * 64 + i * 16 + quad * 4;
      for (int r = 0; r < 4; ++r) {
        float val = acc[i][j][r] + bv;
        if (OUT_BF16)
          ((u16*)outp)[(size_t)(gm + r) * 256 + gn] = f2bf(val);
        else
          ((float*)outp)[(size_t)(gm + r) * 256 + gn] = val;
      }
    }
  }
}

extern "C" void kernel_launch(void* const* d_in, const int* in_sizes, int n_in,
                              void* d_out, int out_size, void* d_ws, size_t ws_size,
                              hipStream_t stream) {
  const float* q  = (const float*)d_in[0];
  const float* k  = (const float*)d_in[1];
  const float* v  = (const float*)d_in[2];
  const float* Wq = (const float*)d_in[4];
  const float* bq = (const float*)d_in[5];
  const float* Wk = (const float*)d_in[6];
  const float* bk = (const float*)d_in[7];
  const float* Wv = (const float*)d_in[8];
  const float* bv = (const float*)d_in[9];
  const float* Wo = (const float*)d_in[10];
  const float* bo = (const float*)d_in[11];

  const size_t MD = (size_t)16384 * 256;
  u16* qp  = (u16*)d_ws;
  u16* kp  = qp + MD;
  u16* vpt = kp + MD;                         // [4][256][4096]
  u16* ctx = vpt + MD;
  u16* wt  = ctx + MD;                        // 4 x 256x256 bf16
  float* ps   = (float*)(wt + 4 * 65536);     // [4][32][4096]
  float* ctxf = ps + (size_t)4 * 32 * 4096;   // [4 kg][4 b][4096][256] fp32 = 64MB
  u16* eb = (u16*)(ctxf + (size_t)16 * 1024 * 1024);  // packed tri [4][528][16384] bf16

  float* zout = (float*)d_out;
  float* attn = zout + (size_t)4 * 4096 * 256;

  k_wt<<<dim3(8, 8, 4), dim3(32, 8), 0, stream>>>(Wq, Wk, Wv, Wo, wt);
  k_pgemm3<<<dim3(2, 128, 3), 256, 0, stream>>>(q, k, v, wt, bq, bk, bv, qp, kp, vpt);
  k_qk<<<dim3(32, 32, 4), 256, 0, stream>>>(qp, kp, eb, attn, ps);
  k_pv2<<<dim3(8, 32, 4), 256, 0, stream>>>(eb, vpt, ps, attn, ctxf);
  k_cvt<<<4096, 256, 0, stream>>>(ctxf, ctx);
  k_gemm<false><<<dim3(2, 128), 256, 0, stream>>>(ctx, wt + 3 * 65536, bo, zout);
}

// Round 8
// 493.559 us; speedup vs baseline: 1.2412x; 1.0012x over previous
//
#include <hip/hip_runtime.h>

// OneHeadAttention: B=4, S=4096, D=256.
// out = [z (4*4096*256 fp32) | attn (4*4096*4096 fp32)]
//
// Pipeline:
//  k_wt      : W* fp32 [k][n] -> bf16 Wt [n][k]
//  k_pgemm3  : q,k,v fp32 -> @ Wt + b -> qp,kp bf16; v-path transposed -> vpt
//  k_qk      : E = exp(qp kp^T/16) causal; lower tiles -> eb bf16 (packed
//              triangular); masked tiles -> attn zeros (nt); ps row-sums.
//              R8: BK=64 reg-staged K-loop, XOR-swizzled LDS (kills the 8-way
//              bank conflict of the 64B-row layout), next-iter loads issued
//              before MFMA (latency hidden), launch_bounds(256,3).
//  k_pv2     : split-K (balanced chunks) x n-split. 256-thread blocks, 4 warps
//              2x2 -> 64q x 64n per warp. LDS double-buffered 64-k half-steps,
//              reg-staged with XOR-swizzled ds_write. Normalize reads A from
//              LDS -> attn fp32 (nt). inv applied in epilogue; plain stores
//              to per-kg ctxf slice.
//  k_cvt     : sum written ctxf slices (chunk predicate) -> bf16 ctx
//  k_gemm    : z = ctx @ Wo + bo

typedef unsigned short u16;
typedef __attribute__((ext_vector_type(8))) short short8;
typedef __attribute__((ext_vector_type(4))) float f32x4;

struct __align__(8) us4 { u16 x, y, z, w; };

#define SEQ 4096
#define DIM 256

__device__ __forceinline__ u16 f2bf(float f) {
  unsigned int u = __float_as_uint(f);
  u += 0x7fffu + ((u >> 16) & 1u);
  return (u16)(u >> 16);
}
__device__ __forceinline__ float bf2f(u16 u) {
  return __uint_as_float(((unsigned int)u) << 16);
}

__device__ __forceinline__ void cp16(const void* g, void* l) {
  __builtin_amdgcn_global_load_lds((const __attribute__((address_space(1))) void*)g,
                                   (__attribute__((address_space(3))) void*)l, 16, 0, 0);
}

// ---------------- weight transpose ----------------
__global__ void k_wt(const float* __restrict__ Wq, const float* __restrict__ Wk,
                     const float* __restrict__ Wv, const float* __restrict__ Wo,
                     u16* __restrict__ wt) {
  __shared__ float t[32][33];
  const float* W = blockIdx.z == 0 ? Wq : blockIdx.z == 1 ? Wk : blockIdx.z == 2 ? Wv : Wo;
  u16* out = wt + (size_t)blockIdx.z * 65536;
  int n0 = blockIdx.x * 32, k0 = blockIdx.y * 32;
  int tx = threadIdx.x, ty = threadIdx.y;
  for (int i = 0; i < 4; i++)
    t[ty + i * 8][tx] = W[(size_t)(k0 + ty + i * 8) * 256 + n0 + tx];
  __syncthreads();
  for (int i = 0; i < 4; i++)
    out[(size_t)(n0 + ty + i * 8) * 256 + k0 + tx] = f2bf(t[tx][ty + i * 8]);
}

// ---------------- projection GEMMs, merged: z=0 -> qp, z=1 -> kp, z=2 -> vpt --
__global__ void k_pgemm3(const float* __restrict__ qin, const float* __restrict__ kin,
                         const float* __restrict__ vin, const u16* __restrict__ wtall,
                         const float* __restrict__ bq, const float* __restrict__ bk,
                         const float* __restrict__ bv,
                         u16* __restrict__ qp, u16* __restrict__ kp,
                         u16* __restrict__ vpt) {
  __shared__ __align__(16) char smem[34816];  // staging 16KB | TRANS epi 34816B
  const int z = blockIdx.z;
  const float* A = z == 0 ? qin : z == 1 ? kin : vin;
  const u16* Wt = wtall + (size_t)z * 65536;
  const float* bias = z == 0 ? bq : z == 1 ? bk : bv;
  u16* outp = z == 0 ? qp : z == 1 ? kp : vpt;
  const bool TRANS = (z == 2);

  u16* Asm = (u16*)smem;
  u16* Bsm = Asm + 4096;
  u16* tb = (u16*)smem;
  const int tid = threadIdx.x;
  const int lane = tid & 63, w = tid >> 6;
  const int wr = w >> 1, wc = w & 1;
  const int quad = lane >> 4, m16 = lane & 15;
  const int m0 = blockIdx.y * 128, n0 = blockIdx.x * 128;

  f32x4 zero = {0.f, 0.f, 0.f, 0.f};
  f32x4 acc[4][4];
  for (int i = 0; i < 4; i++)
    for (int j = 0; j < 4; j++) acc[i][j] = zero;

  for (int kk = 0; kk < 8; ++kk) {
    const int k0 = kk * 32;
    for (int h = 0; h < 2; ++h) {
      int c = tid + h * 256;
      int row = c >> 2, sub = c & 3;
      cp16(Wt + (size_t)(n0 + row) * 256 + k0 + sub * 8, Bsm + c * 8);
    }
    for (int h = 0; h < 4; ++h) {
      int idx = h * 256 + tid;
      int row = idx >> 3, q4 = idx & 7;
      float4 a4 = *(const float4*)(A + (size_t)(m0 + row) * 256 + k0 + q4 * 4);
      us4 o;
      o.x = f2bf(a4.x); o.y = f2bf(a4.y); o.z = f2bf(a4.z); o.w = f2bf(a4.w);
      *(us4*)(Asm + row * 32 + q4 * 4) = o;
    }
    __syncthreads();
    short8 a[4], b[4];
    for (int i = 0; i < 4; ++i)
      a[i] = *(const short8*)(Asm + (wr * 64 + i * 16 + m16) * 32 + quad * 8);
    for (int j = 0; j < 4; ++j)
      b[j] = *(const short8*)(Bsm + (wc * 64 + j * 16 + m16) * 32 + quad * 8);
    for (int i = 0; i < 4; ++i)
      for (int j = 0; j < 4; ++j)
        acc[i][j] = __builtin_amdgcn_mfma_f32_16x16x32_bf16(a[i], b[j], acc[i][j], 0, 0, 0);
    __syncthreads();
  }

  if (!TRANS) {
    for (int j = 0; j < 4; ++j) {
      int gn = n0 + wc * 64 + j * 16 + m16;
      float bvx = bias[gn];
      for (int i = 0; i < 4; ++i) {
        int gm = m0 + wr * 64 + i * 16 + quad * 4;
        for (int r = 0; r < 4; ++r)
          outp[(size_t)(gm + r) * 256 + gn] = f2bf(acc[i][j][r] + bvx);
      }
    }
  } else {
    // transpose epilogue -> vpt[b][n][s]
    for (int j = 0; j < 4; ++j) {
      int cn = wc * 64 + j * 16 + m16;
      float bvx = bias[n0 + cn];
      for (int i = 0; i < 4; ++i) {
        int rm = wr * 64 + i * 16 + quad * 4;
        us4 o;
        o.x = f2bf(acc[i][j][0] + bvx); o.y = f2bf(acc[i][j][1] + bvx);
        o.z = f2bf(acc[i][j][2] + bvx); o.w = f2bf(acc[i][j][3] + bvx);
        *(us4*)(tb + cn * 136 + rm) = o;
      }
    }
    __syncthreads();
    int b = m0 >> 12, s0 = m0 & 4095;
    u16* dst = outp + ((size_t)b << 20);
    for (int it = 0; it < 8; ++it) {
      int idx = it * 256 + tid;
      int n = idx >> 4, m8 = idx & 15;
      short8 v8 = *(const short8*)(tb + n * 136 + m8 * 8);
      *(short8*)(dst + (size_t)(n0 + n) * 4096 + s0 + m8 * 8) = v8;
    }
  }
}

// ---------------- QK^T, exp, causal ----------------------------------------
// eb is PACKED triangular: tile (qt,kt), kt<=qt, at index qt*(qt+1)/2+kt,
// each tile 128x128 bf16 contiguous (32KB).  XCD-chunked swizzle on work id.
// R8 K-loop: BK=64, reg-staged, XOR-swizzled LDS, load/compute overlapped.
__global__ void __launch_bounds__(256, 3) k_qk(const u16* __restrict__ qp,
                                               const u16* __restrict__ kp,
                                               u16* __restrict__ eb,
                                               float* __restrict__ attn,
                                               float* __restrict__ ps) {
  // bijective XCD swizzle: 4096 blocks, 8 XCDs -> each XCD a contiguous chunk
  int lin = blockIdx.x + (blockIdx.y << 5) + (blockIdx.z << 10);
  int wid = (lin & 7) * 512 + (lin >> 3);
  const int kt = wid & 31, qt = (wid >> 5) & 31, bz = wid >> 10;
  const int tid = threadIdx.x;
  const int q0 = qt * 128, k0t = kt * 128;

  if (kt > qt) {  // fully masked: attn zeros only
    float* attnb = attn + ((size_t)bz << 24);
    f32x4 z4 = {0.f, 0.f, 0.f, 0.f};
    for (int s = 0; s < 16; ++s) {
      int idx = tid + s * 256;
      int row = idx >> 5, c4 = idx & 31;
      __builtin_nontemporal_store(z4,
          (f32x4*)(attnb + (size_t)(q0 + row) * 4096 + k0t + c4 * 4));
    }
    return;
  }

  __shared__ __align__(16) char smem[34816];  // staging 32KB (A|B) | epi 34816B
  u16* A_lds = (u16*)smem;          // [128][64] u16, swizzled, 16KB
  u16* B_lds = A_lds + 8192;        // [128][64] u16, swizzled, 16KB
  u16* epi = (u16*)smem;            // reused after MFMA loop
  __shared__ float prow[2][128];

  const int lane = tid & 63, w = tid >> 6;
  const int wr = w >> 1, wc = w & 1;
  const int quad = lane >> 4, m16 = lane & 15;
  const u16* Ab = qp + ((size_t)bz << 20);
  const u16* Bb = kp + ((size_t)bz << 20);

  // staging: 4 chunks of 16B for A and B per thread, rows 0..127, 8 chunks/row
  short8 arg[4], brg[4];
  const int sc = tid & 7;
  int srow[4], soff[4];
  for (int t = 0; t < 4; ++t) {
    srow[t] = (t * 256 + tid) >> 3;
    soff[t] = srow[t] * 64 + ((((sc << 4) ^ ((srow[t] & 7) << 4))) >> 1);
  }

  auto stage_load = [&](int kk) {
    const int k0 = kk * 64;
    for (int t = 0; t < 4; ++t) {
      arg[t] = *(const short8*)(Ab + (size_t)(q0 + srow[t]) * 256 + k0 + sc * 8);
      brg[t] = *(const short8*)(Bb + (size_t)(k0t + srow[t]) * 256 + k0 + sc * 8);
    }
  };
  auto stage_write = [&]() {
    for (int t = 0; t < 4; ++t) {
      *(short8*)(A_lds + soff[t]) = arg[t];
      *(short8*)(B_lds + soff[t]) = brg[t];
    }
  };

  f32x4 zero = {0.f, 0.f, 0.f, 0.f};
  f32x4 acc[4][4];
  for (int i = 0; i < 4; i++)
    for (int j = 0; j < 4; j++) acc[i][j] = zero;

  stage_load(0);
  stage_write();
  __syncthreads();

  for (int kk = 0; kk < 4; ++kk) {
    if (kk + 1 < 4) stage_load(kk + 1);  // in flight during MFMA below
    for (int ks = 0; ks < 2; ++ks) {
      short8 a[4], b[4];
      for (int i = 0; i < 4; ++i) {
        int row = wr * 64 + i * 16 + m16;
        int xb = (ks * 64 + quad * 16) ^ ((row & 7) << 4);
        a[i] = *(const short8*)(A_lds + row * 64 + (xb >> 1));
      }
      for (int j = 0; j < 4; ++j) {
        int n = wc * 64 + j * 16 + m16;
        int xb = (ks * 64 + quad * 16) ^ ((n & 7) << 4);
        b[j] = *(const short8*)(B_lds + n * 64 + (xb >> 1));
      }
      for (int i = 0; i < 4; ++i)
        for (int j = 0; j < 4; ++j)
          acc[i][j] = __builtin_amdgcn_mfma_f32_16x16x32_bf16(a[i], b[j], acc[i][j], 0, 0, 0);
    }
    __syncthreads();                    // all warps' reads of this tile done
    if (kk + 1 < 4) {
      stage_write();
      __syncthreads();                  // writes visible to all warps
    }
  }

  // exp + causal mask + row-sum partials
  float rs[4][4];
  for (int i = 0; i < 4; i++)
    for (int r = 0; r < 4; r++) rs[i][r] = 0.f;
  for (int i = 0; i < 4; ++i) {
    int gq = q0 + wr * 64 + i * 16 + quad * 4;
    for (int j = 0; j < 4; ++j) {
      int gk = k0t + wc * 64 + j * 16 + m16;
      for (int r = 0; r < 4; ++r) {
        float e = (gk <= gq + r) ? __expf(acc[i][j][r] * 0.0625f) : 0.f;
        acc[i][j][r] = e;
        rs[i][r] += e;
      }
    }
  }
  for (int off = 1; off < 16; off <<= 1)
    for (int i = 0; i < 4; ++i)
      for (int r = 0; r < 4; ++r) rs[i][r] += __shfl_xor(rs[i][r], off, 64);
  if (m16 == 0)
    for (int i = 0; i < 4; ++i)
      for (int r = 0; r < 4; ++r)
        prow[wc][wr * 64 + i * 16 + quad * 4 + r] = rs[i][r];

  // dump E bf16 into LDS, then coalesced 16B PLAIN stores to packed eb tile
  // (plain so eb stays L2/L3-resident for pv2's reads)
  for (int i = 0; i < 4; ++i)
    for (int j = 0; j < 4; ++j) {
      int rl = wr * 64 + i * 16 + quad * 4;
      int cl = wc * 64 + j * 16 + m16;
      for (int r = 0; r < 4; ++r) epi[(rl + r) * 136 + cl] = f2bf(acc[i][j][r]);
    }
  __syncthreads();

  u16* ebt = eb + ((size_t)bz * 528 + (size_t)(qt * (qt + 1) / 2 + kt)) * 16384;
  for (int it = 0; it < 8; ++it) {
    int idx = it * 256 + tid;
    int row = idx >> 4, m8 = idx & 15;
    short8 v8 = *(const short8*)(epi + row * 136 + m8 * 8);
    *(short8*)(ebt + row * 128 + m8 * 8) = v8;
  }
  if (tid < 128)
    ps[(size_t)(bz * 32 + kt) * 4096 + q0 + tid] = prow[0][tid] + prow[1][tid];
}

// ---------------- split-K PV, LDS double-buffered half-steps ----------------
// grid x: kg(4) x nh(2); balanced kg chunk = [kg*(qt+1)/4, (kg+1)*(qt+1)/4).
// 256 threads, 4 warps in 2x2 -> 64q x 64n per warp.
// REG-STAGED: linear coalesced global loads -> regs; ds_write_b128 to
// swizzled LDS addr (byte col ^= (row&7)<<4); reads apply same XOR.
__global__ void __launch_bounds__(256) k_pv2(const u16* __restrict__ eb,
                                             const u16* __restrict__ vpt,
                                             const float* __restrict__ ps,
                                             float* __restrict__ attn,
                                             float* __restrict__ ctxf) {
  // bijective XCD swizzle over 1024 blocks
  int lin = blockIdx.x + (blockIdx.y << 3) + (blockIdx.z << 8);
  int wid = (lin & 7) * 128 + (lin >> 3);
  const int nh = wid & 1, kg = (wid >> 1) & 3;
  const int qt = (wid >> 3) & 31, bz = wid >> 8;
  const int nt_lo = (kg * (qt + 1)) >> 2;
  const int nt_hi = ((kg + 1) * (qt + 1)) >> 2;
  if (nt_lo >= nt_hi) return;

  __shared__ u16 A_lds[2][128 * 64];   // 2 x 16KB
  __shared__ u16 B_lds[2][128 * 64];   // 2 x 16KB
  __shared__ float inv_lds[128];

  const int tid = threadIdx.x;
  const int lane = tid & 63, w = tid >> 6;
  const int wr = w >> 1, wc = w & 1;     // 2x2 warps: 64q x 64n each
  const int quad = lane >> 4, m16 = lane & 15;
  const int q0 = qt * 128;
  const u16* ebq = eb + ((size_t)bz * 528 + (size_t)(qt * (qt + 1) / 2)) * 16384;
  float* attnb = attn + ((size_t)bz << 24);
  const u16* vb = vpt + ((size_t)bz << 20) + (size_t)nh * 128 * 4096;

  if (tid < 128) {
    float s = 0.f;
    for (int kt = 0; kt <= qt; ++kt)
      s += ps[(size_t)(bz * 32 + kt) * 4096 + q0 + tid];
    inv_lds[tid] = 1.f / s;
  }

  // staging registers: 4 chunks of 16B each for A and B per thread
  short8 arg[4], brg[4];
  const int sc = tid & 7;                 // 16B chunk in 128B row
  int srow[4], soff[4];
  for (int t = 0; t < 4; ++t) {
    srow[t] = (t * 256 + tid) >> 3;       // 0..127
    soff[t] = srow[t] * 64 + ((((sc << 4) ^ ((srow[t] & 7) << 4))) >> 1);
  }

  auto stage_load = [&](int hh) {
    int t0 = nt_lo + (hh >> 1), h = hh & 1;
    const u16* tile = ebq + (size_t)t0 * 16384 + h * 64;
    int kt0 = t0 * 128 + h * 64;
    for (int t = 0; t < 4; ++t) {
      arg[t] = *(const short8*)(tile + srow[t] * 128 + sc * 8);
      brg[t] = *(const short8*)(vb + (size_t)srow[t] * 4096 + kt0 + sc * 8);
    }
  };
  auto stage_write = [&](int buf) {
    for (int t = 0; t < 4; ++t) {
      *(short8*)(A_lds[buf] + soff[t]) = arg[t];
      *(short8*)(B_lds[buf] + soff[t]) = brg[t];
    }
  };

  const int khalves = (nt_hi - nt_lo) * 2;
  stage_load(0);
  stage_write(0);
  __syncthreads();

  f32x4 zero = {0.f, 0.f, 0.f, 0.f};
  f32x4 acc[4][4];
  for (int i = 0; i < 4; i++)
    for (int j = 0; j < 4; j++) acc[i][j] = zero;

  for (int hh = 0; hh < khalves; ++hh) {
    const int buf = hh & 1;
    if (hh + 1 < khalves) stage_load(hh + 1);  // latency hidden under compute

    // normalize this half's 128 rows -> attn fp32 (nt), 4 chunks/thread
    for (int p = 0; p < 4; ++p) {
      int idx = p * 256 + tid;
      int rl = idx >> 3, c8 = idx & 7;
      int lb = rl * 64 + ((((c8 << 4) ^ ((rl & 7) << 4))) >> 1);
      short8 e8 = *(const short8*)(A_lds[buf] + lb);
      float ivr = inv_lds[rl];
      f32x4 lo, hi;
      for (int t = 0; t < 4; ++t) lo[t] = bf2f((u16)e8[t]) * ivr;
      for (int t = 0; t < 4; ++t) hi[t] = bf2f((u16)e8[t + 4]) * ivr;
      int kcol = (nt_lo + (hh >> 1)) * 128 + (hh & 1) * 64 + (c8 << 3);
      float* dst = attnb + (size_t)(q0 + rl) * 4096 + kcol;
      __builtin_nontemporal_store(lo, (f32x4*)dst);
      __builtin_nontemporal_store(hi, (f32x4*)(dst + 4));
    }

    // MFMA over the 64-k half (2 x 32k steps), 16 MFMA per warp per ks
    for (int ks = 0; ks < 2; ++ks) {
      short8 a[4], b[4];
      for (int i = 0; i < 4; ++i) {
        int row = wr * 64 + i * 16 + m16;
        int xb = (ks * 64 + quad * 16) ^ ((row & 7) << 4);
        a[i] = *(const short8*)(A_lds[buf] + row * 64 + (xb >> 1));
      }
      for (int j = 0; j < 4; ++j) {
        int n = wc * 64 + j * 16 + m16;
        int xb = (ks * 64 + quad * 16) ^ ((n & 7) << 4);
        b[j] = *(const short8*)(B_lds[buf] + n * 64 + (xb >> 1));
      }
      for (int i = 0; i < 4; ++i)
        for (int j = 0; j < 4; ++j)
          acc[i][j] = __builtin_amdgcn_mfma_f32_16x16x32_bf16(a[i], b[j], acc[i][j], 0, 0, 0);
    }

    if (hh + 1 < khalves) stage_write(buf ^ 1);  // WAR-safe: buf^1 readers done
    __syncthreads();  // writes visible before next iter reads buf^1
  }

  // epilogue: scale by inv, plain coalesced stores to this kg's private slice
  float* ctxs = ctxf + ((size_t)(kg * 4 + bz) << 20);
  for (int i = 0; i < 4; ++i) {
    int rl = wr * 64 + i * 16 + quad * 4;
    for (int j = 0; j < 4; ++j) {
      int gn = nh * 128 + wc * 64 + j * 16 + m16;
      for (int r = 0; r < 4; ++r)
        ctxs[(size_t)(q0 + rl + r) * 256 + gn] = acc[i][j][r] * inv_lds[rl + r];
    }
  }
}

// ---------------- sum written ctxf slices -> bf16 ctx ----------------
__global__ void k_cvt(const float* __restrict__ ctxf, u16* __restrict__ ctx) {
  size_t i4 = (size_t)blockIdx.x * 256 + threadIdx.x;  // float4 index over [4][4096][64]
  int bz = (int)(i4 >> 18);
  size_t rem4 = i4 & (((size_t)1 << 18) - 1);
  int qrow = (int)(rem4 >> 6);
  int qt = qrow >> 7;
  const float4* base = (const float4*)ctxf;
  float4 s = make_float4(0.f, 0.f, 0.f, 0.f);
  for (int kg = 0; kg < 4; ++kg) {
    if ((((kg + 1) * (qt + 1)) >> 2) > ((kg * (qt + 1)) >> 2)) {
      float4 t = base[((size_t)(kg * 4 + bz) << 18) + rem4];
      s.x += t.x; s.y += t.y; s.z += t.z; s.w += t.w;
    }
  }
  us4 o;
  o.x = f2bf(s.x); o.y = f2bf(s.y); o.z = f2bf(s.z); o.w = f2bf(s.w);
  ((us4*)ctx)[i4] = o;
}

// ---------------- bf16-input GEMM (final projection) ----------------
template <bool OUT_BF16>
__global__ void k_gemm(const u16* __restrict__ A, const u16* __restrict__ Wt,
                       const float* __restrict__ bias, void* __restrict__ outp) {
  __shared__ u16 Asm[128 * 32];
  __shared__ u16 Bsm[128 * 32];
  const int tid = threadIdx.x;
  const int lane = tid & 63, w = tid >> 6;
  const int wr = w >> 1, wc = w & 1;
  const int quad = lane >> 4, m16 = lane & 15;
  const int m0 = blockIdx.y * 128, n0 = blockIdx.x * 128;

  f32x4 zero = {0.f, 0.f, 0.f, 0.f};
  f32x4 acc[4][4];
  for (int i = 0; i < 4; i++)
    for (int j = 0; j < 4; j++) acc[i][j] = zero;

  for (int kk = 0; kk < 8; ++kk) {
    const int k0 = kk * 32;
    for (int h = 0; h < 2; ++h) {
      int c = tid + h * 256;
      int row = c >> 2, sub = c & 3;
      cp16(A + (size_t)(m0 + row) * 256 + k0 + sub * 8, Asm + c * 8);
      cp16(Wt + (size_t)(n0 + row) * 256 + k0 + sub * 8, Bsm + c * 8);
    }
    __syncthreads();
    short8 a[4], b[4];
    for (int i = 0; i < 4; ++i)
      a[i] = *(const short8*)(Asm + (wr * 64 + i * 16 + m16) * 32 + quad * 8);
    for (int j = 0; j < 4; ++j)
      b[j] = *(const short8*)(Bsm + (wc * 64 + j * 16 + m16) * 32 + quad * 8);
    for (int i = 0; i < 4; ++i)
      for (int j = 0; j < 4; ++j)
        acc[i][j] = __builtin_amdgcn_mfma_f32_16x16x32_bf16(a[i], b[j], acc[i][j], 0, 0, 0);
    __syncthreads();
  }

  for (int j = 0; j < 4; ++j) {
    int gn = n0 + wc * 64 + j * 16 + m16;
    float bv = bias[gn];
    for (int i = 0; i < 4; ++i) {
      int gm = m0 + wr * 64 + i * 16 + quad * 4;
      for (int r = 0; r < 4; ++r) {
        float val = acc[i][j][r] + bv;
        if (OUT_BF16)
          ((u16*)outp)[(size_t)(gm + r) * 256 + gn] = f2bf(val);
        else
          ((float*)outp)[(size_t)(gm + r) * 256 + gn] = val;
      }
    }
  }
}

extern "C" void kernel_launch(void* const* d_in, const int* in_sizes, int n_in,
                              void* d_out, int out_size, void* d_ws, size_t ws_size,
                              hipStream_t stream) {
  const float* q  = (const float*)d_in[0];
  const float* k  = (const float*)d_in[1];
  const float* v  = (const float*)d_in[2];
  const float* Wq = (const float*)d_in[4];
  const float* bq = (const float*)d_in[5];
  const float* Wk = (const float*)d_in[6];
  const float* bk = (const float*)d_in[7];
  const float* Wv = (const float*)d_in[8];
  const float* bv = (const float*)d_in[9];
  const float* Wo = (const float*)d_in[10];
  const float* bo = (const float*)d_in[11];

  const size_t MD = (size_t)16384 * 256;
  u16* qp  = (u16*)d_ws;
  u16* kp  = qp + MD;
  u16* vpt = kp + MD;                         // [4][256][4096]
  u16* ctx = vpt + MD;
  u16* wt  = ctx + MD;                        // 4 x 256x256 bf16
  float* ps   = (float*)(wt + 4 * 65536);     // [4][32][4096]
  float* ctxf = ps + (size_t)4 * 32 * 4096;   // [4 kg][4 b][4096][256] fp32 = 64MB
  u16* eb = (u16*)(ctxf + (size_t)16 * 1024 * 1024);  // packed tri [4][528][16384] bf16

  float* zout = (float*)d_out;
  float* attn = zout + (size_t)4 * 4096 * 256;

  k_wt<<<dim3(8, 8, 4), dim3(32, 8), 0, stream>>>(Wq, Wk, Wv, Wo, wt);
  k_pgemm3<<<dim3(2, 128, 3), 256, 0, stream>>>(q, k, v, wt, bq, bk, bv, qp, kp, vpt);
  k_qk<<<dim3(32, 32, 4), 256, 0, stream>>>(qp, kp, eb, attn, ps);
  k_pv2<<<dim3(8, 32, 4), 256, 0, stream>>>(eb, vpt, ps, attn, ctxf);
  k_cvt<<<4096, 256, 0, stream>>>(ctxf, ctx);
  k_gemm<false><<<dim3(2, 128), 256, 0, stream>>>(ctx, wt + 3 * 65536, bo, zout);
}